// Round 1
// baseline (1216.316 us; speedup 1.0000x reference)
//
#include <hip/hip_runtime.h>
#include <math.h>

typedef float f32x4 __attribute__((ext_vector_type(4)));
typedef short bf16x8 __attribute__((ext_vector_type(8)));

#define DEV static __device__ __forceinline__

constexpr int MROWS = 16384;          // B*T = 256*64
constexpr long long MD = 4194304LL;   // MROWS*256

DEV short f2bf(float f) {
  unsigned u = __float_as_uint(f);
  u += 0x7fffu + ((u >> 16) & 1u);
  return (short)(u >> 16);
}
DEV float wredsum(float v) {
#pragma unroll
  for (int off = 32; off > 0; off >>= 1) v += __shfl_xor(v, off, 64);
  return v;
}
DEV float gelu_f(float x) { return 0.5f * x * (1.f + erff(x * 0.70710678118654752f)); }
DEV float softplus_f(float x) { return (x > 20.f) ? x : log1pf(expf(x)); }
DEV float sigmoid_f(float x) { return 1.f / (1.f + expf(-x)); }

// ---------------------------------------------------------------- GEMM ------
enum { E_NONE = 0, E_BIAS = 1, E_BIAS_RES = 2, E_GELU_BIAS = 3, E_SIM = 4 };

// C[M,N] = epi(A[M,K] @ W[N,K]^T). A,W are f32 in global, converted to bf16
// during LDS staging. 256 threads, 4 waves in 2x2 grid, each wave 64x64 out.
template <int EPI>
__global__ __launch_bounds__(256) void gemm128(
    const float* __restrict__ A, const float* __restrict__ W, float* __restrict__ C,
    const float* __restrict__ bias, const float* __restrict__ res,
    int K, int ldc,
    long long az, long long wz, long long cz, long long bz,
    const float* __restrict__ xa, const float* __restrict__ xt) {
  __shared__ __align__(16) short As[128 * 72];
  __shared__ __align__(16) short Bs[128 * 72];
  const int z = blockIdx.z;
  A += (long long)z * az;
  W += (long long)z * wz;
  C += (long long)z * cz;
  const float* bi = bias ? bias + (long long)z * bz : bias;
  const int tid = threadIdx.x, lane = tid & 63, wid = tid >> 6;
  const int wm = wid >> 1, wn = wid & 1;
  const int rowBase = blockIdx.y * 128, colBase = blockIdx.x * 128;
  f32x4 acc[4][4];
#pragma unroll
  for (int m = 0; m < 4; ++m)
#pragma unroll
    for (int n = 0; n < 4; ++n) acc[m][n] = f32x4{0.f, 0.f, 0.f, 0.f};
  const int sr = tid >> 3, sc = (tid & 7) << 3;
  for (int k0 = 0; k0 < K; k0 += 64) {
#pragma unroll
    for (int p = 0; p < 4; ++p) {
      const int row = p * 32 + sr;
      const float* sa = A + (long long)(rowBase + row) * K + (k0 + sc);
      f32x4 a0 = *(const f32x4*)sa, a1 = *(const f32x4*)(sa + 4);
      bf16x8 pa;
      pa[0] = f2bf(a0[0]); pa[1] = f2bf(a0[1]); pa[2] = f2bf(a0[2]); pa[3] = f2bf(a0[3]);
      pa[4] = f2bf(a1[0]); pa[5] = f2bf(a1[1]); pa[6] = f2bf(a1[2]); pa[7] = f2bf(a1[3]);
      *(bf16x8*)&As[row * 72 + sc] = pa;
      const float* sb = W + (long long)(colBase + row) * K + (k0 + sc);
      f32x4 b0 = *(const f32x4*)sb, b1 = *(const f32x4*)(sb + 4);
      bf16x8 pb;
      pb[0] = f2bf(b0[0]); pb[1] = f2bf(b0[1]); pb[2] = f2bf(b0[2]); pb[3] = f2bf(b0[3]);
      pb[4] = f2bf(b1[0]); pb[5] = f2bf(b1[1]); pb[6] = f2bf(b1[2]); pb[7] = f2bf(b1[3]);
      *(bf16x8*)&Bs[row * 72 + sc] = pb;
    }
    __syncthreads();
#pragma unroll
    for (int ks = 0; ks < 2; ++ks) {
      const int kb = ks * 32 + (lane >> 4) * 8;
      bf16x8 af[4], bw[4];
#pragma unroll
      for (int m = 0; m < 4; ++m)
        af[m] = *(const bf16x8*)&As[(wm * 64 + m * 16 + (lane & 15)) * 72 + kb];
#pragma unroll
      for (int n = 0; n < 4; ++n)
        bw[n] = *(const bf16x8*)&Bs[(wn * 64 + n * 16 + (lane & 15)) * 72 + kb];
#pragma unroll
      for (int m = 0; m < 4; ++m)
#pragma unroll
        for (int n = 0; n < 4; ++n)
          acc[m][n] = __builtin_amdgcn_mfma_f32_16x16x32_bf16(af[m], bw[n], acc[m][n], 0, 0, 0);
    }
    __syncthreads();
  }
  float sps = 0.f;
  if (EPI == E_SIM) sps = softplus_f(xt[0]);
#pragma unroll
  for (int m = 0; m < 4; ++m)
#pragma unroll
    for (int n = 0; n < 4; ++n)
#pragma unroll
      for (int r = 0; r < 4; ++r) {
        const int row = rowBase + wm * 64 + m * 16 + ((lane >> 4) << 2) + r;
        const int col = colBase + wn * 64 + n * 16 + (lane & 15);
        if (col < ldc) {
          float v = acc[m][n][r];
          if (EPI == E_BIAS || EPI == E_BIAS_RES || EPI == E_GELU_BIAS) v += bi[col];
          if (EPI == E_BIAS_RES) v += res[(long long)row * ldc + col];
          if (EPI == E_GELU_BIAS) v = gelu_f(v);
          if (EPI == E_SIM) {
            v = v * sps + bi[col];
            const float al = sigmoid_f(xa[col]);
            v = al * v + (1.f - al) * res[(long long)row * ldc + col];
          }
          C[(long long)row * ldc + col] = v;
        }
      }
}

// ------------------------------------------------------------ elementwise ---
// meta[b][d] = concat(site_emb[site], hour_emb[hour]) @ meta_w^T + meta_b
__global__ __launch_bounds__(256) void meta_kernel(
    const int* __restrict__ site_ids, const int* __restrict__ hours,
    const float* __restrict__ site_emb, const float* __restrict__ hour_emb,
    const float* __restrict__ meta_w, const float* __restrict__ meta_b,
    float* __restrict__ out) {
  const int b = blockIdx.x, d = threadIdx.x;
  const int si = site_ids[b], hr = hours[b];
  const float* mw = meta_w + d * 32;
  float acc = meta_b[d];
#pragma unroll
  for (int m = 0; m < 16; ++m) acc += site_emb[si * 16 + m] * mw[m];
#pragma unroll
  for (int m = 0; m < 16; ++m) acc += hour_emb[hr * 16 + m] * mw[16 + m];
  out[b * 256 + d] = acc;
}

// MODE 0: out = LN(in). MODE 1: out = gelu(LN(in)) + pos[t] + meta[b]
template <int MODE>
__global__ __launch_bounds__(256) void ln_kernel(
    const float* __restrict__ in, float* __restrict__ out,
    const float* __restrict__ g, const float* __restrict__ bta,
    const float* __restrict__ pos, const float* __restrict__ mta) {
  __shared__ float red[4];
  const int row = blockIdx.x, d = threadIdx.x;
  const float v = in[(long long)row * 256 + d];
  float s = wredsum(v);
  if ((d & 63) == 0) red[d >> 6] = s;
  __syncthreads();
  const float mean = (red[0] + red[1] + red[2] + red[3]) * (1.f / 256.f);
  const float c = v - mean;
  __syncthreads();
  float s2 = wredsum(c * c);
  if ((d & 63) == 0) red[d >> 6] = s2;
  __syncthreads();
  const float var = (red[0] + red[1] + red[2] + red[3]) * (1.f / 256.f);
  float y = c * rsqrtf(var + 1e-5f) * g[d] + bta[d];
  if (MODE == 1) y = gelu_f(y) + pos[(row & 63) * 256 + d] + mta[(row >> 6) * 256 + d];
  out[(long long)row * 256 + d] = y;
}

// depthwise causal conv (dir-aware) + SiLU
__global__ __launch_bounds__(256) void conv_kernel(
    const float* __restrict__ xss, const float* __restrict__ cw,
    const float* __restrict__ cb, float* __restrict__ xc) {
  const int row = blockIdx.x, dir = blockIdx.y, d = threadIdx.x;
  const int b = row >> 6, tau = row & 63;
  const float* xs = xss + (long long)dir * MD;
  float acc = cb[dir * 256 + d];
#pragma unroll
  for (int k = 0; k < 4; ++k) {
    const int s = tau - 3 + k;
    if (s >= 0) {
      const int st = dir ? 63 - s : s;
      acc += xs[(long long)(b * 64 + st) * 256 + d] * cw[dir * 1024 + d * 4 + k];
    }
  }
  xc[(long long)dir * MD + (long long)row * 256 + d] = acc * sigmoid_f(acc);
}

// Bm,Cm = xc @ [B_w;C_w]^T   (N=32). 8 rows per block.
__global__ __launch_bounds__(256) void bc_kernel(
    const float* __restrict__ xc, const float* __restrict__ Bw,
    const float* __restrict__ Cw, float* __restrict__ bc) {
  __shared__ float xr[8 * 257];
  __shared__ float wl[32 * 257];
  const int dir = blockIdx.y, tid = threadIdx.x;
  const int rowBase = blockIdx.x * 8;
  const float* xs = xc + (long long)dir * MD + (long long)rowBase * 256;
  for (int idx = tid; idx < 2048; idx += 256) xr[(idx >> 8) * 257 + (idx & 255)] = xs[idx];
  const float* Bd = Bw + dir * 4096;
  const float* Cd = Cw + dir * 4096;
  for (int idx = tid; idx < 8192; idx += 256) {
    const int cc = idx >> 8, k = idx & 255;
    wl[cc * 257 + k] = (cc < 16) ? Bd[cc * 256 + k] : Cd[(cc - 16) * 256 + k];
  }
  __syncthreads();
  const int rr = tid >> 5, cc = tid & 31;
  float acc = 0.f;
#pragma unroll 8
  for (int k = 0; k < 256; ++k) acc += xr[rr * 257 + k] * wl[cc * 257 + k];
  bc[(long long)dir * MROWS * 32 + (long long)(rowBase + rr) * 32 + cc] = acc;
}

// selective scan: thread = (b,d), 64 sequential steps, 16-state in registers.
__global__ __launch_bounds__(256) void scan_kernel(
    const float* __restrict__ dtp, const float* __restrict__ bc,
    const float* __restrict__ x, float* __restrict__ hcat,
    const float* __restrict__ alog, const float* __restrict__ Dpl) {
  __shared__ float bcs[2048];
  const int b = blockIdx.x, dir = blockIdx.y, d = threadIdx.x;
  for (int idx = d; idx < 2048; idx += 256)
    bcs[idx] = bc[(long long)dir * MROWS * 32 + (long long)b * 2048 + idx];
  float an[16];
  const float* al = alog + ((long long)dir * 256 + d) * 16;
#pragma unroll
  for (int n = 0; n < 16; ++n) an[n] = -expf(al[n]);
  const float dp = Dpl[dir * 256 + d];
  float hs[16];
#pragma unroll
  for (int n = 0; n < 16; ++n) hs[n] = 0.f;
  __syncthreads();
  const float* dtr = dtp + (long long)dir * MD + (long long)b * 64 * 256 + d;
  for (int tau = 0; tau < 64; ++tau) {
    const float draw = dtr[tau * 256];
    const float dtv = softplus_f(draw);
    const int to = dir ? 63 - tau : tau;
    const float xv = x[(long long)(b * 64 + to) * 256 + d];
    const float u = xv * dtv;
    float y = 0.f;
#pragma unroll
    for (int n = 0; n < 16; ++n) {
      const float dA = expf(an[n] * dtv);
      hs[n] = hs[n] * dA + u * bcs[tau * 32 + n];
      y += hs[n] * bcs[tau * 32 + 16 + n];
    }
    hcat[(long long)(b * 64 + to) * 512 + dir * 256 + d] = y + xv * dp;
  }
}

// attention: 1 wave per (b, head); lane = query row; k/v in LDS; f32.
__global__ __launch_bounds__(64) void attn_kernel(
    const float* __restrict__ qkv, float* __restrict__ out) {
  __shared__ __align__(16) float ks[64 * 68];
  __shared__ __align__(16) float vs[64 * 68];
  const int b = blockIdx.x, h = blockIdx.y, lane = threadIdx.x;
  const long long rb = (long long)b * 64;
  const float* qrow = qkv + (rb + lane) * 768 + h * 64;
  const float* krow = qrow + 256;
  const float* vrow = qrow + 512;
  float q[64], s[64], o[64];
#pragma unroll
  for (int e = 0; e < 64; e += 4) {
    f32x4 t = *(const f32x4*)(qrow + e);
    q[e] = t[0]; q[e + 1] = t[1]; q[e + 2] = t[2]; q[e + 3] = t[3];
    *(f32x4*)&ks[lane * 68 + e] = *(const f32x4*)(krow + e);
    *(f32x4*)&vs[lane * 68 + e] = *(const f32x4*)(vrow + e);
  }
  __syncthreads();
  for (int j = 0; j < 64; ++j) {
    float a0 = 0.f, a1 = 0.f, a2 = 0.f, a3 = 0.f;
#pragma unroll
    for (int e = 0; e < 64; e += 4) {
      f32x4 kv = *(const f32x4*)&ks[j * 68 + e];
      a0 += q[e] * kv[0]; a1 += q[e + 1] * kv[1];
      a2 += q[e + 2] * kv[2]; a3 += q[e + 3] * kv[3];
    }
    s[j] = (a0 + a1 + a2 + a3) * 0.125f;
  }
  float m = s[0];
#pragma unroll
  for (int j = 1; j < 64; ++j) m = fmaxf(m, s[j]);
  float sum = 0.f;
#pragma unroll
  for (int j = 0; j < 64; ++j) { s[j] = expf(s[j] - m); sum += s[j]; }
  const float inv = 1.f / sum;
#pragma unroll
  for (int e = 0; e < 64; ++e) o[e] = 0.f;
  for (int j = 0; j < 64; ++j) {
    const float p = s[j] * inv;
#pragma unroll
    for (int e = 0; e < 64; e += 4) {
      f32x4 vv = *(const f32x4*)&vs[j * 68 + e];
      o[e] += p * vv[0]; o[e + 1] += p * vv[1];
      o[e + 2] += p * vv[2]; o[e + 3] += p * vv[3];
    }
  }
  float* orow = out + (rb + lane) * 256 + h * 64;
#pragma unroll
  for (int e = 0; e < 64; e += 4) {
    f32x4 t = {o[e], o[e + 1], o[e + 2], o[e + 3]};
    *(f32x4*)(orow + e) = t;
  }
}

// row-l2norm of h -> hn; also copy h to out1 (second model output)
__global__ __launch_bounds__(256) void hn_kernel(
    const float* __restrict__ in, float* __restrict__ hn, float* __restrict__ out1) {
  __shared__ float red[4];
  const int row = blockIdx.x, d = threadIdx.x;
  const float v = in[(long long)row * 256 + d];
  float s = wredsum(v * v);
  if ((d & 63) == 0) red[d >> 6] = s;
  __syncthreads();
  const float ss = red[0] + red[1] + red[2] + red[3];
  const float inv = 1.f / fmaxf(sqrtf(ss), 1e-12f);
  hn[(long long)row * 256 + d] = v * inv;
  out1[(long long)row * 256 + d] = v;
}

// l2norm prototypes into padded [256,256] buffer (rows >=234 zeroed)
__global__ __launch_bounds__(256) void protonorm_kernel(
    const float* __restrict__ proto, float* __restrict__ pn) {
  __shared__ float red[4];
  const int c = blockIdx.x, d = threadIdx.x;
  const float v = (c < 234) ? proto[(long long)c * 256 + d] : 0.f;
  float s = wredsum(v * v);
  if ((d & 63) == 0) red[d >> 6] = s;
  __syncthreads();
  const float ss = red[0] + red[1] + red[2] + red[3];
  const float inv = (c < 234) ? 1.f / fmaxf(sqrtf(ss), 1e-12f) : 0.f;
  pn[(long long)c * 256 + d] = v * inv;
}

// ------------------------------------------------------------------ host ----
extern "C" void kernel_launch(void* const* d_in, const int* in_sizes, int n_in,
                              void* d_out, int out_size, void* d_ws, size_t ws_size,
                              hipStream_t stream) {
  const float* emb       = (const float*)d_in[0];
  const float* perch     = (const float*)d_in[1];
  const int*   site_ids  = (const int*)d_in[2];
  const int*   hours     = (const int*)d_in[3];
  const float* in_w      = (const float*)d_in[4];
  const float* in_b      = (const float*)d_in[5];
  const float* ln0_g     = (const float*)d_in[6];
  const float* ln0_b     = (const float*)d_in[7];
  const float* pos_enc   = (const float*)d_in[8];
  const float* site_emb  = (const float*)d_in[9];
  const float* hour_emb  = (const float*)d_in[10];
  const float* meta_w    = (const float*)d_in[11];
  const float* meta_b    = (const float*)d_in[12];
  const float* ssm_in_w  = (const float*)d_in[13];
  const float* ssm_cw    = (const float*)d_in[14];
  const float* ssm_cb    = (const float*)d_in[15];
  const float* ssm_dt_w  = (const float*)d_in[16];
  const float* ssm_dt_b  = (const float*)d_in[17];
  const float* ssm_Alog  = (const float*)d_in[18];
  const float* ssm_Dp    = (const float*)d_in[19];
  const float* ssm_B_w   = (const float*)d_in[20];
  const float* ssm_C_w   = (const float*)d_in[21];
  const float* merge_w   = (const float*)d_in[22];
  const float* merge_b   = (const float*)d_in[23];
  const float* ln_g      = (const float*)d_in[24];
  const float* ln_b      = (const float*)d_in[25];
  const float* qkv_w     = (const float*)d_in[26];
  const float* qkv_b     = (const float*)d_in[27];
  const float* ao_w      = (const float*)d_in[28];
  const float* ao_b      = (const float*)d_in[29];
  const float* ca1_g     = (const float*)d_in[30];
  const float* ca1_b     = (const float*)d_in[31];
  const float* ffn_w1    = (const float*)d_in[32];
  const float* ffn_b1    = (const float*)d_in[33];
  const float* ffn_w2    = (const float*)d_in[34];
  const float* ffn_b2    = (const float*)d_in[35];
  const float* ca2_g     = (const float*)d_in[36];
  const float* ca2_b     = (const float*)d_in[37];
  const float* protos    = (const float*)d_in[38];
  const float* ptemp     = (const float*)d_in[39];
  const float* cbias     = (const float*)d_in[40];
  const float* falpha    = (const float*)d_in[41];

  float* out0 = (float*)d_out;                    // species_logits [16384,234]
  float* out1 = out0 + (long long)MROWS * 234;    // h              [16384,256]

  float* ws = (float*)d_ws;
  float* w_meta = ws;                 // 65536
  float* w_h    = ws + 65536;         // MD
  float* w_tpre = w_h + MD;           // MD
  float* w_ar   = w_tpre + MD;        // arena
  float* w_xss  = w_ar;               // 2*MD (also dtp)
  float* w_xc   = w_ar + 2 * MD;      // 2*MD (also hcat)
  float* w_bc   = w_ar + 4 * MD;      // 2*M*32 = 1048576
  float* w_z    = w_ar;               // MD
  float* w_qkv  = w_ar + MD;          // 12582912
  float* w_mid  = w_ar + MD;          // 8388608
  float* w_hn   = w_ar;               // MD
  float* w_pn   = w_ar + 4 * MD + (long long)MROWS * 64;  // 65536

  const dim3 blk(256);

  // meta + input projection + LN/GELU/pos/meta
  meta_kernel<<<256, blk, 0, stream>>>(site_ids, hours, site_emb, hour_emb,
                                       meta_w, meta_b, w_meta);
  gemm128<E_BIAS><<<dim3(2, 128, 1), blk, 0, stream>>>(
      emb, in_w, w_tpre, in_b, nullptr, 1536, 256, 0, 0, 0, 0, nullptr, nullptr);
  ln_kernel<1><<<MROWS, blk, 0, stream>>>(w_tpre, w_h, ln0_g, ln0_b, pos_enc, w_meta);

  // SSM layers
  for (int l = 0; l < 2; ++l) {
    const float* inw_l = ssm_in_w + (long long)l * 262144;   // [2,512,256]
    const float* cw_l  = ssm_cw + l * 2048;
    const float* cb_l  = ssm_cb + l * 512;
    const float* dtw_l = ssm_dt_w + (long long)l * 131072;
    const float* dtb_l = ssm_dt_b + l * 512;
    const float* Bw_l  = ssm_B_w + l * 8192;
    const float* Cw_l  = ssm_C_w + l * 8192;
    const float* Al_l  = ssm_Alog + l * 8192;
    const float* Dp_l  = ssm_Dp + l * 512;

    // x_ssm (both dirs): first 256 rows of in_w per dir
    gemm128<E_NONE><<<dim3(2, 128, 2), blk, 0, stream>>>(
        w_h, inw_l, w_xss, nullptr, nullptr, 256, 256,
        0LL, 131072LL, MD, 0LL, nullptr, nullptr);
    conv_kernel<<<dim3(MROWS, 2), blk, 0, stream>>>(w_xss, cw_l, cb_l, w_xc);
    // dt pre-activation (softplus in scan); dtp overwrites xss arena
    gemm128<E_BIAS><<<dim3(2, 128, 2), blk, 0, stream>>>(
        w_xc, dtw_l, w_xss, dtb_l, nullptr, 256, 256,
        MD, 65536LL, MD, 256LL, nullptr, nullptr);
    bc_kernel<<<dim3(2048, 2), blk, 0, stream>>>(w_xc, Bw_l, Cw_l, w_bc);
    // scan: writes hcat over xc arena (xc fully consumed)
    scan_kernel<<<dim3(256, 2), blk, 0, stream>>>(w_xss, w_bc, w_h, w_xc, Al_l, Dp_l);
    // merge + residual, then LN
    gemm128<E_BIAS_RES><<<dim3(2, 128, 1), blk, 0, stream>>>(
        w_xc, merge_w + (long long)l * 131072, w_tpre, merge_b + l * 256, w_h,
        512, 256, 0, 0, 0, 0, nullptr, nullptr);
    ln_kernel<0><<<MROWS, blk, 0, stream>>>(w_tpre, w_h, ln_g + l * 256, ln_b + l * 256,
                                            nullptr, nullptr);
  }

  // cross attention
  ln_kernel<0><<<MROWS, blk, 0, stream>>>(w_h, w_z, ca1_g, ca1_b, nullptr, nullptr);
  gemm128<E_BIAS><<<dim3(6, 128, 1), blk, 0, stream>>>(
      w_z, qkv_w, w_qkv, qkv_b, nullptr, 256, 768, 0, 0, 0, 0, nullptr, nullptr);
  attn_kernel<<<dim3(256, 4), dim3(64), 0, stream>>>(w_qkv, w_tpre);
  gemm128<E_BIAS_RES><<<dim3(2, 128, 1), blk, 0, stream>>>(
      w_tpre, ao_w, w_h, ao_b, w_h, 256, 256, 0, 0, 0, 0, nullptr, nullptr);

  // FFN
  ln_kernel<0><<<MROWS, blk, 0, stream>>>(w_h, w_z, ca2_g, ca2_b, nullptr, nullptr);
  gemm128<E_GELU_BIAS><<<dim3(4, 128, 1), blk, 0, stream>>>(
      w_z, ffn_w1, w_mid, ffn_b1, nullptr, 256, 512, 0, 0, 0, 0, nullptr, nullptr);
  gemm128<E_BIAS_RES><<<dim3(2, 128, 1), blk, 0, stream>>>(
      w_mid, ffn_w2, w_h, ffn_b2, w_h, 512, 256, 0, 0, 0, 0, nullptr, nullptr);

  // prototype head
  protonorm_kernel<<<256, blk, 0, stream>>>(protos, w_pn);
  hn_kernel<<<MROWS, blk, 0, stream>>>(w_h, w_hn, out1);
  gemm128<E_SIM><<<dim3(2, 128, 1), blk, 0, stream>>>(
      w_hn, w_pn, out0, cbias, perch, 256, 234, 0, 0, 0, 0, falpha, ptemp);

  (void)in_sizes; (void)n_in; (void)out_size; (void)ws_size;
}

// Round 5
// 983.471 us; speedup vs baseline: 1.2368x; 1.2368x over previous
//
#include <hip/hip_runtime.h>
#include <math.h>

typedef float f32x4 __attribute__((ext_vector_type(4)));
typedef short bf16x8 __attribute__((ext_vector_type(8)));

#define DEV static __device__ __forceinline__

constexpr int MROWS = 16384;            // B*T = 256*64
constexpr long long MD = 4194304LL;     // MROWS*256
constexpr long long DTZ = 4718592LL;    // MROWS*288
constexpr float L2E = 1.44269504088896f;
constexpr float LN2 = 0.69314718055995f;

DEV short f2bf(float f) {
  unsigned u = __float_as_uint(f);
  u += 0x7fffu + ((u >> 16) & 1u);
  return (short)(u >> 16);
}
DEV float wredsum(float v) {
#pragma unroll
  for (int off = 32; off > 0; off >>= 1) v += __shfl_xor(v, off, 64);
  return v;
}
DEV float gelu_f(float x) { return 0.5f * x * (1.f + erff(x * 0.70710678118654752f)); }
DEV float softplus_fast(float x) {
  return (x > 20.f) ? x : log2f(1.f + exp2f(x * L2E)) * LN2;
}
DEV float sigmoid_fast(float x) { return 1.f / (1.f + exp2f(-x * L2E)); }

// ---------------------------------------------------------------- GEMM ------
enum { E_NONE = 0, E_BIAS = 1, E_BIAS_RES = 2, E_GELU_BIAS = 3, E_SIM = 4, E_CONV = 5 };

// C[M,N] = epi(A[M,K] @ W[N,K]^T). A,W f32 in global, bf16 in LDS.
// 256 threads, 4 waves 2x2, each wave 64x64 out. E_CONV: epilogue stages the
// 128x128 tile to LDS (rows = 2 whole sequences) and applies causal depthwise
// conv + SiLU, direction z (reversed iteration), writing xc in scan order.
template <int EPI>
__global__ __launch_bounds__(256) void gemm128(
    const float* __restrict__ A, const float* __restrict__ W, float* __restrict__ C,
    const float* __restrict__ bias, const float* __restrict__ res,
    int K, int ldc,
    long long az, long long wz, long long cz, long long bz,
    const float* __restrict__ xa, const float* __restrict__ xt) {
  constexpr int SBYTES = (EPI == E_CONV) ? 65536 : 36864;
  __shared__ __align__(16) char smem[SBYTES];
  short* As = (short*)smem;            // 128*72 shorts
  short* Bs = As + 128 * 72;           // 128*72 shorts
  const int z = blockIdx.z;
  A += (long long)z * az;
  W += (long long)z * wz;
  C += (long long)z * cz;
  const float* bi = bias ? bias + (long long)z * bz : bias;
  const int tid = threadIdx.x, lane = tid & 63, wid = tid >> 6;
  const int wm = wid >> 1, wn = wid & 1;
  const int rowBase = blockIdx.y * 128, colBase = blockIdx.x * 128;
  f32x4 acc[4][4];
#pragma unroll
  for (int m = 0; m < 4; ++m)
#pragma unroll
    for (int n = 0; n < 4; ++n) acc[m][n] = f32x4{0.f, 0.f, 0.f, 0.f};
  const int sr = tid >> 3, sc = (tid & 7) << 3;
  for (int k0 = 0; k0 < K; k0 += 64) {
#pragma unroll
    for (int p = 0; p < 4; ++p) {
      const int row = p * 32 + sr;
      const float* sa = A + (long long)(rowBase + row) * K + (k0 + sc);
      f32x4 a0 = *(const f32x4*)sa, a1 = *(const f32x4*)(sa + 4);
      bf16x8 pa;
      pa[0] = f2bf(a0[0]); pa[1] = f2bf(a0[1]); pa[2] = f2bf(a0[2]); pa[3] = f2bf(a0[3]);
      pa[4] = f2bf(a1[0]); pa[5] = f2bf(a1[1]); pa[6] = f2bf(a1[2]); pa[7] = f2bf(a1[3]);
      *(bf16x8*)&As[row * 72 + sc] = pa;
      const float* sb = W + (long long)(colBase + row) * K + (k0 + sc);
      f32x4 b0 = *(const f32x4*)sb, b1 = *(const f32x4*)(sb + 4);
      bf16x8 pb;
      pb[0] = f2bf(b0[0]); pb[1] = f2bf(b0[1]); pb[2] = f2bf(b0[2]); pb[3] = f2bf(b0[3]);
      pb[4] = f2bf(b1[0]); pb[5] = f2bf(b1[1]); pb[6] = f2bf(b1[2]); pb[7] = f2bf(b1[3]);
      *(bf16x8*)&Bs[row * 72 + sc] = pb;
    }
    __syncthreads();
#pragma unroll
    for (int ks = 0; ks < 2; ++ks) {
      const int kb = ks * 32 + (lane >> 4) * 8;
      bf16x8 af[4], bw[4];
#pragma unroll
      for (int m = 0; m < 4; ++m)
        af[m] = *(const bf16x8*)&As[(wm * 64 + m * 16 + (lane & 15)) * 72 + kb];
#pragma unroll
      for (int n = 0; n < 4; ++n)
        bw[n] = *(const bf16x8*)&Bs[(wn * 64 + n * 16 + (lane & 15)) * 72 + kb];
#pragma unroll
      for (int m = 0; m < 4; ++m)
#pragma unroll
        for (int n = 0; n < 4; ++n)
          acc[m][n] = __builtin_amdgcn_mfma_f32_16x16x32_bf16(af[m], bw[n], acc[m][n], 0, 0, 0);
    }
    __syncthreads();
  }
  if constexpr (EPI == E_CONV) {
    // stage full 128x128 f32 tile (union over As/Bs — safe after last barrier)
    float* SX = (float*)smem;  // [128][128]
#pragma unroll
    for (int m = 0; m < 4; ++m)
#pragma unroll
      for (int n = 0; n < 4; ++n)
#pragma unroll
        for (int r = 0; r < 4; ++r) {
          const int rl = wm * 64 + m * 16 + ((lane >> 4) << 2) + r;
          const int cl = wn * 64 + n * 16 + (lane & 15);
          SX[rl * 128 + cl] = acc[m][n][r];
        }
    __syncthreads();
    const int c = tid & 127, hh = tid >> 7;
    const int gcol = colBase + c;
    const float* cwp = xa + (long long)z * 1024 + gcol * 4;   // conv_w[dir][d][4]
    const float w0 = cwp[0], w1 = cwp[1], w2 = cwp[2], w3 = cwp[3];
    const float cbv = xt[z * 256 + gcol];
    const long long orow0 = rowBase + hh * 64;                // = b*64
    float x0 = 0.f, x1 = 0.f, x2 = 0.f;
    for (int t = 0; t < 64; ++t) {
      const int src = z ? (63 - t) : t;
      const float x3 = SX[(hh * 64 + src) * 128 + c];
      float a = cbv + x0 * w0 + x1 * w1 + x2 * w2 + x3 * w3;
      a = a * sigmoid_fast(a);
      C[(orow0 + t) * (long long)ldc + gcol] = a;
      x0 = x1; x1 = x2; x2 = x3;
    }
    return;
  }
  float sps = 0.f;
  if (EPI == E_SIM) sps = softplus_fast(xt[0]);
#pragma unroll
  for (int m = 0; m < 4; ++m)
#pragma unroll
    for (int n = 0; n < 4; ++n)
#pragma unroll
      for (int r = 0; r < 4; ++r) {
        const int row = rowBase + wm * 64 + m * 16 + ((lane >> 4) << 2) + r;
        const int col = colBase + wn * 64 + n * 16 + (lane & 15);
        if (col < ldc) {
          float v = acc[m][n][r];
          if (EPI == E_BIAS || EPI == E_BIAS_RES || EPI == E_GELU_BIAS) v += bi[col];
          if (EPI == E_BIAS_RES) v += res[(long long)row * ldc + col];
          if (EPI == E_GELU_BIAS) v = gelu_f(v);
          if (EPI == E_SIM) {
            v = v * sps + bi[col];
            const float al = 1.f / (1.f + expf(-xa[col]));
            v = al * v + (1.f - al) * res[(long long)row * ldc + col];
          }
          C[(long long)row * ldc + col] = v;
        }
      }
}

// --------------------------------------------------------------- helpers ----
// concat [dt_w; B_w; C_w] -> wcat[(l,dir)][288 rows][256], bias -> bcat[288]
__global__ __launch_bounds__(256) void prep_wcat(
    const float* __restrict__ dt_w, const float* __restrict__ dt_b,
    const float* __restrict__ Bw, const float* __restrict__ Cw,
    float* __restrict__ wcat, float* __restrict__ bcat) {
  const int r = blockIdx.x, ld = blockIdx.y, tid = threadIdx.x;
  float v;
  if (r < 256)      v = dt_w[(long long)ld * 65536 + r * 256 + tid];
  else if (r < 272) v = Bw[(long long)ld * 4096 + (r - 256) * 256 + tid];
  else              v = Cw[(long long)ld * 4096 + (r - 272) * 256 + tid];
  wcat[(long long)ld * 98304 + (long long)r * 256 + tid] = v;
  if (r == 0) bcat[ld * 288 + tid] = dt_b[ld * 256 + tid];
  if (r == 1 && tid < 32) bcat[ld * 288 + 256 + tid] = 0.f;
}

// meta[b][d] = concat(site_emb[site], hour_emb[hour]) @ meta_w^T + meta_b
__global__ __launch_bounds__(256) void meta_kernel(
    const int* __restrict__ site_ids, const int* __restrict__ hours,
    const float* __restrict__ site_emb, const float* __restrict__ hour_emb,
    const float* __restrict__ meta_w, const float* __restrict__ meta_b,
    float* __restrict__ out) {
  const int b = blockIdx.x, d = threadIdx.x;
  const int si = site_ids[b], hr = hours[b];
  const float* mw = meta_w + d * 32;
  float acc = meta_b[d];
#pragma unroll
  for (int m = 0; m < 16; ++m) acc += site_emb[si * 16 + m] * mw[m];
#pragma unroll
  for (int m = 0; m < 16; ++m) acc += hour_emb[hr * 16 + m] * mw[16 + m];
  out[b * 256 + d] = acc;
}

// MODE 0: out = LN(in). MODE 1: out = gelu(LN(in)) + pos[t] + meta[b]
template <int MODE>
__global__ __launch_bounds__(256) void ln_kernel(
    const float* __restrict__ in, float* __restrict__ out,
    const float* __restrict__ g, const float* __restrict__ bta,
    const float* __restrict__ pos, const float* __restrict__ mta) {
  __shared__ float red[4];
  const int row = blockIdx.x, d = threadIdx.x;
  const float v = in[(long long)row * 256 + d];
  float s = wredsum(v);
  if ((d & 63) == 0) red[d >> 6] = s;
  __syncthreads();
  const float mean = (red[0] + red[1] + red[2] + red[3]) * (1.f / 256.f);
  const float c = v - mean;
  __syncthreads();
  float s2 = wredsum(c * c);
  if ((d & 63) == 0) red[d >> 6] = s2;
  __syncthreads();
  const float var = (red[0] + red[1] + red[2] + red[3]) * (1.f / 256.f);
  float y = c * rsqrtf(var + 1e-5f) * g[d] + bta[d];
  if (MODE == 1) y = gelu_f(y) + pos[(row & 63) * 256 + d] + mta[(row >> 6) * 256 + d];
  out[(long long)row * 256 + d] = y;
}

// selective scan: thread = (b,d); dt/B/C from fused dtbc [16384,288] per dir.
__global__ __launch_bounds__(256) void scan_kernel(
    const float* __restrict__ dtbc, const float* __restrict__ x,
    float* __restrict__ hcat, const float* __restrict__ alog,
    const float* __restrict__ Dpl) {
  __shared__ float bcs[2048];
  const int b = blockIdx.x, dir = blockIdx.y, d = threadIdx.x;
  const float* dz = dtbc + (long long)dir * DTZ;
  for (int idx = d; idx < 2048; idx += 256)
    bcs[idx] = dz[(long long)(b * 64 + (idx >> 5)) * 288 + 256 + (idx & 31)];
  float an2[16];
  const float* al = alog + ((long long)dir * 256 + d) * 16;
#pragma unroll
  for (int n = 0; n < 16; ++n) an2[n] = -expf(al[n]) * L2E;
  const float dp = Dpl[dir * 256 + d];
  float hs[16];
#pragma unroll
  for (int n = 0; n < 16; ++n) hs[n] = 0.f;
  __syncthreads();
  const float* dtr = dz + (long long)b * 64 * 288 + d;
  const float* xr = x + (long long)b * 64 * 256 + d;
  float draw = dtr[0];
  float xv = xr[(dir ? 63 : 0) * 256];
  for (int tau = 0; tau < 64; ++tau) {
    float drawN = 0.f, xvN = 0.f;
    if (tau < 63) {
      drawN = dtr[(tau + 1) * 288];
      xvN = xr[(dir ? (62 - tau) : (tau + 1)) * 256];
    }
    const float dtv = softplus_fast(draw);
    const float u = xv * dtv;
    float y = 0.f;
#pragma unroll
    for (int n = 0; n < 16; ++n) {
      const float dA = exp2f(an2[n] * dtv);
      hs[n] = hs[n] * dA + u * bcs[tau * 32 + n];
      y += hs[n] * bcs[tau * 32 + 16 + n];
    }
    const int to = dir ? 63 - tau : tau;
    hcat[(long long)(b * 64 + to) * 512 + dir * 256 + d] = y + xv * dp;
    draw = drawN; xv = xvN;
  }
}

// attention: 1 wave per (b,head); scores in LDS (no scratch), coalesced I/O.
__global__ __launch_bounds__(64) void attn_kernel(
    const float* __restrict__ qkv, float* __restrict__ out) {
  __shared__ float ks[64 * 65], vs[64 * 65], ss[64 * 65];
  const int b = blockIdx.x, h = blockIdx.y, lane = threadIdx.x;
  const long long rb = (long long)b * 64;
  const float* base = qkv + rb * 768 + h * 64;
  for (int r = 0; r < 64; ++r) {
    ss[r * 65 + lane] = base[(long long)r * 768 + lane];
    ks[r * 65 + lane] = base[(long long)r * 768 + 256 + lane];
    vs[r * 65 + lane] = base[(long long)r * 768 + 512 + lane];
  }
  __syncthreads();
  float q[64];
#pragma unroll
  for (int e = 0; e < 64; ++e) q[e] = ss[lane * 65 + e];
  __syncthreads();
  float mx = -1e30f;
  for (int j = 0; j < 64; ++j) {
    float a = 0.f;
#pragma unroll
    for (int e = 0; e < 64; ++e) a += q[e] * ks[j * 65 + e];
    a *= 0.125f;
    ss[lane * 65 + j] = a;
    mx = fmaxf(mx, a);
  }
  float sum = 0.f;
  for (int j = 0; j < 64; ++j) {
    const float p = exp2f((ss[lane * 65 + j] - mx) * L2E);
    ss[lane * 65 + j] = p;
    sum += p;
  }
  const float inv = 1.f / sum;
  float o[64];
#pragma unroll
  for (int e = 0; e < 64; ++e) o[e] = 0.f;
  for (int j = 0; j < 64; ++j) {
    const float p = ss[lane * 65 + j] * inv;
#pragma unroll
    for (int e = 0; e < 64; ++e) o[e] += p * vs[j * 65 + e];
  }
  __syncthreads();
#pragma unroll
  for (int e = 0; e < 64; ++e) ss[lane * 65 + e] = o[e];
  __syncthreads();
  for (int r = 0; r < 64; ++r)
    out[(rb + r) * 256 + h * 64 + lane] = ss[r * 65 + lane];
}

// row-l2norm of h -> hn; also copy h to out1 (second model output)
__global__ __launch_bounds__(256) void hn_kernel(
    const float* __restrict__ in, float* __restrict__ hn, float* __restrict__ out1) {
  __shared__ float red[4];
  const int row = blockIdx.x, d = threadIdx.x;
  const float v = in[(long long)row * 256 + d];
  float s = wredsum(v * v);
  if ((d & 63) == 0) red[d >> 6] = s;
  __syncthreads();
  const float ss = red[0] + red[1] + red[2] + red[3];
  const float inv = 1.f / fmaxf(sqrtf(ss), 1e-12f);
  hn[(long long)row * 256 + d] = v * inv;
  out1[(long long)row * 256 + d] = v;
}

// l2norm prototypes into padded [256,256] buffer (rows >=234 zeroed)
__global__ __launch_bounds__(256) void protonorm_kernel(
    const float* __restrict__ proto, float* __restrict__ pn) {
  __shared__ float red[4];
  const int c = blockIdx.x, d = threadIdx.x;
  const float v = (c < 234) ? proto[(long long)c * 256 + d] : 0.f;
  float s = wredsum(v * v);
  if ((d & 63) == 0) red[d >> 6] = s;
  __syncthreads();
  const float ss = red[0] + red[1] + red[2] + red[3];
  const float inv = (c < 234) ? 1.f / fmaxf(sqrtf(ss), 1e-12f) : 0.f;
  pn[(long long)c * 256 + d] = v * inv;
}

// ------------------------------------------------------------------ host ----
extern "C" void kernel_launch(void* const* d_in, const int* in_sizes, int n_in,
                              void* d_out, int out_size, void* d_ws, size_t ws_size,
                              hipStream_t stream) {
  const float* emb       = (const float*)d_in[0];
  const float* perch     = (const float*)d_in[1];
  const int*   site_ids  = (const int*)d_in[2];
  const int*   hours     = (const int*)d_in[3];
  const float* in_w      = (const float*)d_in[4];
  const float* in_b      = (const float*)d_in[5];
  const float* ln0_g     = (const float*)d_in[6];
  const float* ln0_b     = (const float*)d_in[7];
  const float* pos_enc   = (const float*)d_in[8];
  const float* site_emb  = (const float*)d_in[9];
  const float* hour_emb  = (const float*)d_in[10];
  const float* meta_w    = (const float*)d_in[11];
  const float* meta_b    = (const float*)d_in[12];
  const float* ssm_in_w  = (const float*)d_in[13];
  const float* ssm_cw    = (const float*)d_in[14];
  const float* ssm_cb    = (const float*)d_in[15];
  const float* ssm_dt_w  = (const float*)d_in[16];
  const float* ssm_dt_b  = (const float*)d_in[17];
  const float* ssm_Alog  = (const float*)d_in[18];
  const float* ssm_Dp    = (const float*)d_in[19];
  const float* ssm_B_w   = (const float*)d_in[20];
  const float* ssm_C_w   = (const float*)d_in[21];
  const float* merge_w   = (const float*)d_in[22];
  const float* merge_b   = (const float*)d_in[23];
  const float* ln_g      = (const float*)d_in[24];
  const float* ln_b      = (const float*)d_in[25];
  const float* qkv_w     = (const float*)d_in[26];
  const float* qkv_b     = (const float*)d_in[27];
  const float* ao_w      = (const float*)d_in[28];
  const float* ao_b      = (const float*)d_in[29];
  const float* ca1_g     = (const float*)d_in[30];
  const float* ca1_b     = (const float*)d_in[31];
  const float* ffn_w1    = (const float*)d_in[32];
  const float* ffn_b1    = (const float*)d_in[33];
  const float* ffn_w2    = (const float*)d_in[34];
  const float* ffn_b2    = (const float*)d_in[35];
  const float* ca2_g     = (const float*)d_in[36];
  const float* ca2_b     = (const float*)d_in[37];
  const float* protos    = (const float*)d_in[38];
  const float* ptemp     = (const float*)d_in[39];
  const float* cbias     = (const float*)d_in[40];
  const float* falpha    = (const float*)d_in[41];

  float* out0 = (float*)d_out;                    // species_logits [16384,234]
  float* out1 = out0 + (long long)MROWS * 234;    // h              [16384,256]

  float* ws = (float*)d_ws;
  float* w_meta = ws;                         // 65536
  float* w_h    = ws + 65536;                 // MD
  float* w_tpre = w_h + MD;                   // MD
  float* w_ar   = w_tpre + MD;                // arena
  // SSM phase:
  float* w_xc   = w_ar;                       // 2*MD (conv out; later hcat)
  float* w_dtbc = w_ar + 2 * MD;              // 2*DTZ = 9437184
  float* w_wcat = w_ar + 2 * MD + 2 * DTZ;    // 4*98304 = 393216
  float* w_bcat = w_wcat + 393216;            // 4*288
  // attention/FFN phase (reuse arena):
  float* w_z    = w_ar;                       // MD
  float* w_qkv  = w_ar + MD;                  // 12582912
  float* w_mid  = w_ar + MD;                  // 8388608
  // head phase:
  float* w_hn   = w_ar;                       // MD
  float* w_pn   = w_ar + MD;                  // 65536

  const dim3 blk(256);

  prep_wcat<<<dim3(288, 4), blk, 0, stream>>>(ssm_dt_w, ssm_dt_b, ssm_B_w,
                                              ssm_C_w, w_wcat, w_bcat);
  meta_kernel<<<256, blk, 0, stream>>>(site_ids, hours, site_emb, hour_emb,
                                       meta_w, meta_b, w_meta);
  gemm128<E_BIAS><<<dim3(2, 128, 1), blk, 0, stream>>>(
      emb, in_w, w_tpre, in_b, nullptr, 1536, 256, 0, 0, 0, 0, nullptr, nullptr);
  ln_kernel<1><<<MROWS, blk, 0, stream>>>(w_tpre, w_h, ln0_g, ln0_b, pos_enc, w_meta);

  for (int l = 0; l < 2; ++l) {
    const float* inw_l = ssm_in_w + (long long)l * 262144;   // [2,512,256]
    const float* cw_l  = ssm_cw + l * 2048;
    const float* cb_l  = ssm_cb + l * 512;
    const float* Al_l  = ssm_Alog + l * 8192;
    const float* Dp_l  = ssm_Dp + l * 512;

    // x_ssm + causal depthwise conv + SiLU fused; output in scan order
    gemm128<E_CONV><<<dim3(2, 128, 2), blk, 0, stream>>>(
        w_h, inw_l, w_xc, nullptr, nullptr, 256, 256,
        0LL, 131072LL, MD, 0LL, cw_l, cb_l);
    // fused dt|B|C projection: [16384,288] per dir
    gemm128<E_BIAS><<<dim3(3, 128, 2), blk, 0, stream>>>(
        w_xc, w_wcat + (long long)l * 196608, w_dtbc,
        w_bcat + l * 576, nullptr, 256, 288,
        MD, 98304LL, DTZ, 288LL, nullptr, nullptr);
    // scan writes hcat over the xc arena (xc consumed by dtbc gemm)
    scan_kernel<<<dim3(256, 2), blk, 0, stream>>>(w_dtbc, w_h, w_xc, Al_l, Dp_l);
    gemm128<E_BIAS_RES><<<dim3(2, 128, 1), blk, 0, stream>>>(
        w_xc, merge_w + (long long)l * 131072, w_tpre, merge_b + l * 256, w_h,
        512, 256, 0, 0, 0, 0, nullptr, nullptr);
    ln_kernel<0><<<MROWS, blk, 0, stream>>>(w_tpre, w_h, ln_g + l * 256, ln_b + l * 256,
                                            nullptr, nullptr);
  }

  // cross attention
  ln_kernel<0><<<MROWS, blk, 0, stream>>>(w_h, w_z, ca1_g, ca1_b, nullptr, nullptr);
  gemm128<E_BIAS><<<dim3(6, 128, 1), blk, 0, stream>>>(
      w_z, qkv_w, w_qkv, qkv_b, nullptr, 256, 768, 0, 0, 0, 0, nullptr, nullptr);
  attn_kernel<<<dim3(256, 4), dim3(64), 0, stream>>>(w_qkv, w_tpre);
  gemm128<E_BIAS_RES><<<dim3(2, 128, 1), blk, 0, stream>>>(
      w_tpre, ao_w, w_h, ao_b, w_h, 256, 256, 0, 0, 0, 0, nullptr, nullptr);

  // FFN
  ln_kernel<0><<<MROWS, blk, 0, stream>>>(w_h, w_z, ca2_g, ca2_b, nullptr, nullptr);
  gemm128<E_GELU_BIAS><<<dim3(4, 128, 1), blk, 0, stream>>>(
      w_z, ffn_w1, w_mid, ffn_b1, nullptr, 256, 512, 0, 0, 0, 0, nullptr, nullptr);
  gemm128<E_BIAS_RES><<<dim3(2, 128, 1), blk, 0, stream>>>(
      w_mid, ffn_w2, w_h, ffn_b2, w_h, 512, 256, 0, 0, 0, 0, nullptr, nullptr);

  // prototype head
  protonorm_kernel<<<256, blk, 0, stream>>>(protos, w_pn);
  hn_kernel<<<MROWS, blk, 0, stream>>>(w_h, w_hn, out1);
  gemm128<E_SIM><<<dim3(2, 128, 1), blk, 0, stream>>>(
      w_hn, w_pn, out0, cbias, perch, 256, 234, 0, 0, 0, 0, falpha, ptemp);

  (void)in_sizes; (void)n_in; (void)out_size; (void)ws_size;
}

// Round 6
// 825.582 us; speedup vs baseline: 1.4733x; 1.1912x over previous
//
#include <hip/hip_runtime.h>
#include <math.h>

typedef float f32x4 __attribute__((ext_vector_type(4)));
typedef short bf16x8 __attribute__((ext_vector_type(8)));

#define DEV static __device__ __forceinline__

constexpr int MROWS = 16384;            // B*T = 256*64
constexpr long long MD = 4194304LL;     // MROWS*256
constexpr long long DTZ = 4718592LL;    // MROWS*288
constexpr float L2E = 1.44269504088896f;
constexpr float LN2 = 0.69314718055995f;

DEV short f2bf(float f) {
  unsigned u = __float_as_uint(f);
  u += 0x7fffu + ((u >> 16) & 1u);
  return (short)(u >> 16);
}
DEV float wredsum(float v) {
#pragma unroll
  for (int off = 32; off > 0; off >>= 1) v += __shfl_xor(v, off, 64);
  return v;
}
DEV float gelu_f(float x) { return 0.5f * x * (1.f + erff(x * 0.70710678118654752f)); }
DEV float softplus_fast(float x) {
  return (x > 20.f) ? x : log2f(1.f + exp2f(x * L2E)) * LN2;
}
DEV float sigmoid_fast(float x) { return 1.f / (1.f + exp2f(-x * L2E)); }

// ---------------------------------------------------------------- GEMM ------
enum { E_NONE = 0, E_BIAS = 1, E_BIAS_RES = 2, E_GELU_BIAS = 3, E_SIM = 4, E_CONV = 5 };

// C[M,N] = epi(A[M,K] @ W[N,K]^T). Tile 128x64, 256 threads (4 waves 2x2,
// wave tile 64x32). Register-prefetch pipeline: tile k+1 global loads issue
// before compute(k) barrier -> HBM latency hides under MFMA + other blocks.
// LDS 27.6KB -> 5 blocks/CU (20 waves/CU). B-row staging clamped to ldc-1.
template <int EPI>
__global__ __launch_bounds__(256) void gemm128(
    const float* __restrict__ A, const float* __restrict__ W, float* __restrict__ C,
    const float* __restrict__ bias, const float* __restrict__ res,
    int K, int ldc,
    long long az, long long wz, long long cz, long long bz,
    const float* __restrict__ xa, const float* __restrict__ xt) {
  constexpr int SBYTES = (EPI == E_CONV) ? 33280 : 27648;
  __shared__ __align__(16) char smem[SBYTES];
  short* As = (short*)smem;            // [128][72]
  short* Bs = As + 128 * 72;           // [64][72]
  const int z = blockIdx.z;
  A += (long long)z * az;
  W += (long long)z * wz;
  C += (long long)z * cz;
  const float* bi = bias ? bias + (long long)z * bz : bias;
  const int tid = threadIdx.x, lane = tid & 63, wid = tid >> 6;
  const int wm = wid >> 1, wn = wid & 1;
  const int rowBase = blockIdx.y * 128, colBase = blockIdx.x * 64;
  f32x4 acc[4][2];
#pragma unroll
  for (int m = 0; m < 4; ++m)
#pragma unroll
    for (int n = 0; n < 2; ++n) acc[m][n] = f32x4{0.f, 0.f, 0.f, 0.f};
  const int sr = tid >> 3, sc = (tid & 7) << 3;
  f32x4 ra[4][2], rb[2][2];

#define GLOAD(K0)                                                              \
  {                                                                            \
    _Pragma("unroll") for (int p = 0; p < 4; ++p) {                            \
      const float* sa = A + (long long)(rowBase + p * 32 + sr) * K + ((K0) + sc); \
      ra[p][0] = *(const f32x4*)sa;                                            \
      ra[p][1] = *(const f32x4*)(sa + 4);                                      \
    }                                                                          \
    _Pragma("unroll") for (int q = 0; q < 2; ++q) {                            \
      int wr = colBase + q * 32 + sr;                                          \
      wr = (wr < ldc) ? wr : (ldc - 1);                                        \
      const float* sb = W + (long long)wr * K + ((K0) + sc);                   \
      rb[q][0] = *(const f32x4*)sb;                                            \
      rb[q][1] = *(const f32x4*)(sb + 4);                                      \
    }                                                                          \
  }

  GLOAD(0);
  const int nsteps = K >> 6;
  for (int s = 0; s < nsteps; ++s) {
    __syncthreads();   // LDS free: reads of step s-1 complete
#pragma unroll
    for (int p = 0; p < 4; ++p) {
      bf16x8 pa;
      pa[0] = f2bf(ra[p][0][0]); pa[1] = f2bf(ra[p][0][1]);
      pa[2] = f2bf(ra[p][0][2]); pa[3] = f2bf(ra[p][0][3]);
      pa[4] = f2bf(ra[p][1][0]); pa[5] = f2bf(ra[p][1][1]);
      pa[6] = f2bf(ra[p][1][2]); pa[7] = f2bf(ra[p][1][3]);
      *(bf16x8*)&As[(p * 32 + sr) * 72 + sc] = pa;
    }
#pragma unroll
    for (int q = 0; q < 2; ++q) {
      bf16x8 pb;
      pb[0] = f2bf(rb[q][0][0]); pb[1] = f2bf(rb[q][0][1]);
      pb[2] = f2bf(rb[q][0][2]); pb[3] = f2bf(rb[q][0][3]);
      pb[4] = f2bf(rb[q][1][0]); pb[5] = f2bf(rb[q][1][1]);
      pb[6] = f2bf(rb[q][1][2]); pb[7] = f2bf(rb[q][1][3]);
      *(bf16x8*)&Bs[(q * 32 + sr) * 72 + sc] = pb;
    }
    if (s + 1 < nsteps) GLOAD((s + 1) << 6);   // in flight during compute
    __syncthreads();   // staged tile visible
#pragma unroll
    for (int ks = 0; ks < 2; ++ks) {
      const int kb = ks * 32 + (lane >> 4) * 8;
      bf16x8 af[4], bw[2];
#pragma unroll
      for (int m = 0; m < 4; ++m)
        af[m] = *(const bf16x8*)&As[(wm * 64 + m * 16 + (lane & 15)) * 72 + kb];
#pragma unroll
      for (int n = 0; n < 2; ++n)
        bw[n] = *(const bf16x8*)&Bs[(wn * 32 + n * 16 + (lane & 15)) * 72 + kb];
#pragma unroll
      for (int m = 0; m < 4; ++m)
#pragma unroll
        for (int n = 0; n < 2; ++n)
          acc[m][n] = __builtin_amdgcn_mfma_f32_16x16x32_bf16(af[m], bw[n], acc[m][n], 0, 0, 0);
    }
  }
#undef GLOAD

  if constexpr (EPI == E_CONV) {
    // stage 128x64 f32 tile (stride 65) then 4-tap causal FIR + SiLU.
    float* SX = (float*)smem;
    __syncthreads();   // ds_reads of last step done before overwrite
#pragma unroll
    for (int m = 0; m < 4; ++m)
#pragma unroll
      for (int n = 0; n < 2; ++n)
#pragma unroll
        for (int r = 0; r < 4; ++r) {
          const int rl = wm * 64 + m * 16 + ((lane >> 4) << 2) + r;
          const int cl = wn * 32 + n * 16 + (lane & 15);
          SX[rl * 65 + cl] = acc[m][n][r];
        }
    __syncthreads();
    const int c = tid & 63, rg = tid >> 6;
    const int gcol = colBase + c;
    const float* cwp = xa + (long long)z * 1024 + gcol * 4;   // conv_w[dir][d][4]
    const float wv0 = cwp[0], wv1 = cwp[1], wv2 = cwp[2], wv3 = cwp[3];
    const float cbv = xt[z * 256 + gcol];
#pragma unroll 4
    for (int i = 0; i < 32; ++i) {
      const int lr = rg * 32 + i;
      const int seq = lr >> 6, tau = lr & 63;
      float a = cbv;
#pragma unroll
      for (int k = 0; k < 4; ++k) {
        const int sidx = tau - 3 + k;
        if (sidx >= 0) {
          const int srow = seq * 64 + (z ? 63 - sidx : sidx);
          const float wk = (k == 0) ? wv0 : (k == 1) ? wv1 : (k == 2) ? wv2 : wv3;
          a += SX[srow * 65 + c] * wk;
        }
      }
      a = a * sigmoid_fast(a);
      C[(long long)(rowBase + lr) * ldc + gcol] = a;
    }
    return;
  }

  float sps = 0.f;
  if (EPI == E_SIM) sps = softplus_fast(xt[0]);
#pragma unroll
  for (int m = 0; m < 4; ++m)
#pragma unroll
    for (int n = 0; n < 2; ++n)
#pragma unroll
      for (int r = 0; r < 4; ++r) {
        const int row = rowBase + wm * 64 + m * 16 + ((lane >> 4) << 2) + r;
        const int col = colBase + wn * 32 + n * 16 + (lane & 15);
        if (col < ldc) {
          float v = acc[m][n][r];
          if (EPI == E_BIAS || EPI == E_BIAS_RES || EPI == E_GELU_BIAS) v += bi[col];
          if (EPI == E_BIAS_RES) v += res[(long long)row * ldc + col];
          if (EPI == E_GELU_BIAS) v = gelu_f(v);
          if (EPI == E_SIM) {
            v = v * sps + bi[col];
            const float al = 1.f / (1.f + expf(-xa[col]));
            v = al * v + (1.f - al) * res[(long long)row * ldc + col];
          }
          C[(long long)row * ldc + col] = v;
        }
      }
}

// --------------------------------------------------------------- helpers ----
// concat [dt_w; B_w; C_w] -> wcat[(l,dir)][288 rows][256], bias -> bcat[288]
__global__ __launch_bounds__(256) void prep_wcat(
    const float* __restrict__ dt_w, const float* __restrict__ dt_b,
    const float* __restrict__ Bw, const float* __restrict__ Cw,
    float* __restrict__ wcat, float* __restrict__ bcat) {
  const int r = blockIdx.x, ld = blockIdx.y, tid = threadIdx.x;
  float v;
  if (r < 256)      v = dt_w[(long long)ld * 65536 + r * 256 + tid];
  else if (r < 272) v = Bw[(long long)ld * 4096 + (r - 256) * 256 + tid];
  else              v = Cw[(long long)ld * 4096 + (r - 272) * 256 + tid];
  wcat[(long long)ld * 98304 + (long long)r * 256 + tid] = v;
  if (r == 0) bcat[ld * 288 + tid] = dt_b[ld * 256 + tid];
  if (r == 1 && tid < 32) bcat[ld * 288 + 256 + tid] = 0.f;
}

// meta[b][d] = concat(site_emb[site], hour_emb[hour]) @ meta_w^T + meta_b
__global__ __launch_bounds__(256) void meta_kernel(
    const int* __restrict__ site_ids, const int* __restrict__ hours,
    const float* __restrict__ site_emb, const float* __restrict__ hour_emb,
    const float* __restrict__ meta_w, const float* __restrict__ meta_b,
    float* __restrict__ out) {
  const int b = blockIdx.x, d = threadIdx.x;
  const int si = site_ids[b], hr = hours[b];
  const float* mw = meta_w + d * 32;
  float acc = meta_b[d];
#pragma unroll
  for (int m = 0; m < 16; ++m) acc += site_emb[si * 16 + m] * mw[m];
#pragma unroll
  for (int m = 0; m < 16; ++m) acc += hour_emb[hr * 16 + m] * mw[16 + m];
  out[b * 256 + d] = acc;
}

// LN, 4 rows/block (1 wave/row), f32x4 loads, no barriers.
// MODE 0: out = LN(in). MODE 1: out = gelu(LN(in)) + pos[t] + meta[b]
template <int MODE>
__global__ __launch_bounds__(256) void ln_kernel(
    const float* __restrict__ in, float* __restrict__ out,
    const float* __restrict__ g, const float* __restrict__ bta,
    const float* __restrict__ pos, const float* __restrict__ mta) {
  const int row = blockIdx.x * 4 + (threadIdx.x >> 6);
  const int lane = threadIdx.x & 63;
  const long long base = (long long)row * 256 + lane * 4;
  f32x4 v = *(const f32x4*)(in + base);
  const float mean = wredsum(v[0] + v[1] + v[2] + v[3]) * (1.f / 256.f);
  f32x4 c = {v[0] - mean, v[1] - mean, v[2] - mean, v[3] - mean};
  const float var = wredsum(c[0] * c[0] + c[1] * c[1] + c[2] * c[2] + c[3] * c[3]) * (1.f / 256.f);
  const float rs = rsqrtf(var + 1e-5f);
  const f32x4 gv = *(const f32x4*)(g + lane * 4);
  const f32x4 bv = *(const f32x4*)(bta + lane * 4);
  f32x4 y;
#pragma unroll
  for (int j = 0; j < 4; ++j) y[j] = c[j] * rs * gv[j] + bv[j];
  if (MODE == 1) {
    const f32x4 pv = *(const f32x4*)(pos + (row & 63) * 256 + lane * 4);
    const f32x4 mv = *(const f32x4*)(mta + (row >> 6) * 256 + lane * 4);
#pragma unroll
    for (int j = 0; j < 4; ++j) y[j] = gelu_f(y[j]) + pv[j] + mv[j];
  }
  *(f32x4*)(out + base) = y;
}

// selective scan: thread = (b,d); dt/B/C from fused dtbc [16384,288] per dir.
__global__ __launch_bounds__(256) void scan_kernel(
    const float* __restrict__ dtbc, const float* __restrict__ x,
    float* __restrict__ hcat, const float* __restrict__ alog,
    const float* __restrict__ Dpl) {
  __shared__ float bcs[2048];
  const int b = blockIdx.x, dir = blockIdx.y, d = threadIdx.x;
  const float* dz = dtbc + (long long)dir * DTZ;
  for (int idx = d; idx < 2048; idx += 256)
    bcs[idx] = dz[(long long)(b * 64 + (idx >> 5)) * 288 + 256 + (idx & 31)];
  float an2[16];
  const float* al = alog + ((long long)dir * 256 + d) * 16;
#pragma unroll
  for (int n = 0; n < 16; ++n) an2[n] = -expf(al[n]) * L2E;
  const float dp = Dpl[dir * 256 + d];
  float hs[16];
#pragma unroll
  for (int n = 0; n < 16; ++n) hs[n] = 0.f;
  __syncthreads();
  const float* dtr = dz + (long long)b * 64 * 288 + d;
  const float* xr = x + (long long)b * 64 * 256 + d;
  float draw = dtr[0];
  float xv = xr[(dir ? 63 : 0) * 256];
  for (int tau = 0; tau < 64; ++tau) {
    float drawN = 0.f, xvN = 0.f;
    if (tau < 63) {
      drawN = dtr[(tau + 1) * 288];
      xvN = xr[(dir ? (62 - tau) : (tau + 1)) * 256];
    }
    const float dtv = softplus_fast(draw);
    const float u = xv * dtv;
    float y = 0.f;
#pragma unroll
    for (int n = 0; n < 16; ++n) {
      const float dA = exp2f(an2[n] * dtv);
      hs[n] = hs[n] * dA + u * bcs[tau * 32 + n];
      y += hs[n] * bcs[tau * 32 + 16 + n];
    }
    const int to = dir ? 63 - tau : tau;
    hcat[(long long)(b * 64 + to) * 512 + dir * 256 + d] = y + xv * dp;
    draw = drawN; xv = xvN;
  }
}

// attention: 1 wave per (b,head); scores in LDS (no scratch), coalesced I/O.
__global__ __launch_bounds__(64) void attn_kernel(
    const float* __restrict__ qkv, float* __restrict__ out) {
  __shared__ float ks[64 * 65], vs[64 * 65], ss[64 * 65];
  const int b = blockIdx.x, h = blockIdx.y, lane = threadIdx.x;
  const long long rb = (long long)b * 64;
  const float* base = qkv + rb * 768 + h * 64;
  for (int r = 0; r < 64; ++r) {
    ss[r * 65 + lane] = base[(long long)r * 768 + lane];
    ks[r * 65 + lane] = base[(long long)r * 768 + 256 + lane];
    vs[r * 65 + lane] = base[(long long)r * 768 + 512 + lane];
  }
  __syncthreads();
  float q[64];
#pragma unroll
  for (int e = 0; e < 64; ++e) q[e] = ss[lane * 65 + e];
  __syncthreads();
  float mx = -1e30f;
  for (int j = 0; j < 64; ++j) {
    float a = 0.f;
#pragma unroll
    for (int e = 0; e < 64; ++e) a += q[e] * ks[j * 65 + e];
    a *= 0.125f;
    ss[lane * 65 + j] = a;
    mx = fmaxf(mx, a);
  }
  float sum = 0.f;
  for (int j = 0; j < 64; ++j) {
    const float p = exp2f((ss[lane * 65 + j] - mx) * L2E);
    ss[lane * 65 + j] = p;
    sum += p;
  }
  const float inv = 1.f / sum;
  float o[64];
#pragma unroll
  for (int e = 0; e < 64; ++e) o[e] = 0.f;
  for (int j = 0; j < 64; ++j) {
    const float p = ss[lane * 65 + j] * inv;
#pragma unroll
    for (int e = 0; e < 64; ++e) o[e] += p * vs[j * 65 + e];
  }
  __syncthreads();
#pragma unroll
  for (int e = 0; e < 64; ++e) ss[lane * 65 + e] = o[e];
  __syncthreads();
  for (int r = 0; r < 64; ++r)
    out[(rb + r) * 256 + h * 64 + lane] = ss[r * 65 + lane];
}

// row-l2norm of h -> hn; also copy h to out1. 4 rows/block, f32x4.
__global__ __launch_bounds__(256) void hn_kernel(
    const float* __restrict__ in, float* __restrict__ hn, float* __restrict__ out1) {
  const int row = blockIdx.x * 4 + (threadIdx.x >> 6);
  const int lane = threadIdx.x & 63;
  const long long base = (long long)row * 256 + lane * 4;
  f32x4 v = *(const f32x4*)(in + base);
  const float ss = wredsum(v[0] * v[0] + v[1] * v[1] + v[2] * v[2] + v[3] * v[3]);
  const float inv = 1.f / fmaxf(sqrtf(ss), 1e-12f);
  f32x4 y = {v[0] * inv, v[1] * inv, v[2] * inv, v[3] * inv};
  *(f32x4*)(hn + base) = y;
  *(f32x4*)(out1 + base) = v;
}

// l2norm prototypes into padded [256,256] buffer (rows >=234 zeroed)
__global__ __launch_bounds__(256) void protonorm_kernel(
    const float* __restrict__ proto, float* __restrict__ pn) {
  __shared__ float red[4];
  const int c = blockIdx.x, d = threadIdx.x;
  const float v = (c < 234) ? proto[(long long)c * 256 + d] : 0.f;
  float s = wredsum(v * v);
  if ((d & 63) == 0) red[d >> 6] = s;
  __syncthreads();
  const float ss = red[0] + red[1] + red[2] + red[3];
  const float inv = (c < 234) ? 1.f / fmaxf(sqrtf(ss), 1e-12f) : 0.f;
  pn[(long long)c * 256 + d] = v * inv;
}

// ------------------------------------------------------------------ host ----
extern "C" void kernel_launch(void* const* d_in, const int* in_sizes, int n_in,
                              void* d_out, int out_size, void* d_ws, size_t ws_size,
                              hipStream_t stream) {
  const float* emb       = (const float*)d_in[0];
  const float* perch     = (const float*)d_in[1];
  const int*   site_ids  = (const int*)d_in[2];
  const int*   hours     = (const int*)d_in[3];
  const float* in_w      = (const float*)d_in[4];
  const float* in_b      = (const float*)d_in[5];
  const float* ln0_g     = (const float*)d_in[6];
  const float* ln0_b     = (const float*)d_in[7];
  const float* pos_enc   = (const float*)d_in[8];
  const float* site_emb  = (const float*)d_in[9];
  const float* hour_emb  = (const float*)d_in[10];
  const float* meta_w    = (const float*)d_in[11];
  const float* meta_b    = (const float*)d_in[12];
  const float* ssm_in_w  = (const float*)d_in[13];
  const float* ssm_cw    = (const float*)d_in[14];
  const float* ssm_cb    = (const float*)d_in[15];
  const float* ssm_dt_w  = (const float*)d_in[16];
  const float* ssm_dt_b  = (const float*)d_in[17];
  const float* ssm_Alog  = (const float*)d_in[18];
  const float* ssm_Dp    = (const float*)d_in[19];
  const float* ssm_B_w   = (const float*)d_in[20];
  const float* ssm_C_w   = (const float*)d_in[21];
  const float* merge_w   = (const float*)d_in[22];
  const float* merge_b   = (const float*)d_in[23];
  const float* ln_g      = (const float*)d_in[24];
  const float* ln_b      = (const float*)d_in[25];
  const float* qkv_w     = (const float*)d_in[26];
  const float* qkv_b     = (const float*)d_in[27];
  const float* ao_w      = (const float*)d_in[28];
  const float* ao_b      = (const float*)d_in[29];
  const float* ca1_g     = (const float*)d_in[30];
  const float* ca1_b     = (const float*)d_in[31];
  const float* ffn_w1    = (const float*)d_in[32];
  const float* ffn_b1    = (const float*)d_in[33];
  const float* ffn_w2    = (const float*)d_in[34];
  const float* ffn_b2    = (const float*)d_in[35];
  const float* ca2_g     = (const float*)d_in[36];
  const float* ca2_b     = (const float*)d_in[37];
  const float* protos    = (const float*)d_in[38];
  const float* ptemp     = (const float*)d_in[39];
  const float* cbias     = (const float*)d_in[40];
  const float* falpha    = (const float*)d_in[41];

  float* out0 = (float*)d_out;                    // species_logits [16384,234]
  float* out1 = out0 + (long long)MROWS * 234;    // h              [16384,256]

  float* ws = (float*)d_ws;
  float* w_meta = ws;                         // 65536
  float* w_h    = ws + 65536;                 // MD
  float* w_tpre = w_h + MD;                   // MD
  float* w_ar   = w_tpre + MD;                // arena
  // SSM phase:
  float* w_xc   = w_ar;                       // 2*MD (conv out; later hcat)
  float* w_dtbc = w_ar + 2 * MD;              // 2*DTZ = 9437184
  float* w_wcat = w_ar + 2 * MD + 2 * DTZ;    // 4*98304 = 393216
  float* w_bcat = w_wcat + 393216;            // 4*288
  // attention/FFN phase (reuse arena):
  float* w_z    = w_ar;                       // MD
  float* w_qkv  = w_ar + MD;                  // 12582912
  float* w_mid  = w_ar + MD;                  // 8388608
  // head phase:
  float* w_hn   = w_ar;                       // MD
  float* w_pn   = w_ar + MD;                  // 65536

  const dim3 blk(256);

  prep_wcat<<<dim3(288, 4), blk, 0, stream>>>(ssm_dt_w, ssm_dt_b, ssm_B_w,
                                              ssm_C_w, w_wcat, w_bcat);
  meta_kernel<<<256, blk, 0, stream>>>(site_ids, hours, site_emb, hour_emb,
                                       meta_w, meta_b, w_meta);
  gemm128<E_BIAS><<<dim3(4, 128, 1), blk, 0, stream>>>(
      emb, in_w, w_tpre, in_b, nullptr, 1536, 256, 0, 0, 0, 0, nullptr, nullptr);
  ln_kernel<1><<<MROWS / 4, blk, 0, stream>>>(w_tpre, w_h, ln0_g, ln0_b, pos_enc, w_meta);

  for (int l = 0; l < 2; ++l) {
    const float* inw_l = ssm_in_w + (long long)l * 262144;   // [2,512,256]
    const float* cw_l  = ssm_cw + l * 2048;
    const float* cb_l  = ssm_cb + l * 512;
    const float* Al_l  = ssm_Alog + l * 8192;
    const float* Dp_l  = ssm_Dp + l * 512;

    // x_ssm + causal depthwise conv + SiLU fused; output in scan order
    gemm128<E_CONV><<<dim3(4, 128, 2), blk, 0, stream>>>(
        w_h, inw_l, w_xc, nullptr, nullptr, 256, 256,
        0LL, 131072LL, MD, 0LL, cw_l, cb_l);
    // fused dt|B|C projection: [16384,288] per dir
    gemm128<E_BIAS><<<dim3(5, 128, 2), blk, 0, stream>>>(
        w_xc, w_wcat + (long long)l * 196608, w_dtbc,
        w_bcat + l * 576, nullptr, 256, 288,
        MD, 98304LL, DTZ, 288LL, nullptr, nullptr);
    // scan writes hcat over the xc arena (xc consumed by dtbc gemm)
    scan_kernel<<<dim3(256, 2), blk, 0, stream>>>(w_dtbc, w_h, w_xc, Al_l, Dp_l);
    gemm128<E_BIAS_RES><<<dim3(4, 128, 1), blk, 0, stream>>>(
        w_xc, merge_w + (long long)l * 131072, w_tpre, merge_b + l * 256, w_h,
        512, 256, 0, 0, 0, 0, nullptr, nullptr);
    ln_kernel<0><<<MROWS / 4, blk, 0, stream>>>(w_tpre, w_h, ln_g + l * 256, ln_b + l * 256,
                                                nullptr, nullptr);
  }

  // cross attention
  ln_kernel<0><<<MROWS / 4, blk, 0, stream>>>(w_h, w_z, ca1_g, ca1_b, nullptr, nullptr);
  gemm128<E_BIAS><<<dim3(12, 128, 1), blk, 0, stream>>>(
      w_z, qkv_w, w_qkv, qkv_b, nullptr, 256, 768, 0, 0, 0, 0, nullptr, nullptr);
  attn_kernel<<<dim3(256, 4), dim3(64), 0, stream>>>(w_qkv, w_tpre);
  gemm128<E_BIAS_RES><<<dim3(4, 128, 1), blk, 0, stream>>>(
      w_tpre, ao_w, w_h, ao_b, w_h, 256, 256, 0, 0, 0, 0, nullptr, nullptr);

  // FFN
  ln_kernel<0><<<MROWS / 4, blk, 0, stream>>>(w_h, w_z, ca2_g, ca2_b, nullptr, nullptr);
  gemm128<E_GELU_BIAS><<<dim3(8, 128, 1), blk, 0, stream>>>(
      w_z, ffn_w1, w_mid, ffn_b1, nullptr, 256, 512, 0, 0, 0, 0, nullptr, nullptr);
  gemm128<E_BIAS_RES><<<dim3(4, 128, 1), blk, 0, stream>>>(
      w_mid, ffn_w2, w_h, ffn_b2, w_h, 512, 256, 0, 0, 0, 0, nullptr, nullptr);

  // prototype head
  protonorm_kernel<<<256, blk, 0, stream>>>(protos, w_pn);
  hn_kernel<<<MROWS / 4, blk, 0, stream>>>(w_h, w_hn, out1);
  gemm128<E_SIM><<<dim3(4, 128, 1), blk, 0, stream>>>(
      w_hn, w_pn, out0, cbias, perch, 256, 234, 0, 0, 0, 0, falpha, ptemp);

  (void)in_sizes; (void)n_in; (void)out_size; (void)ws_size;
}

// Round 8
// 770.492 us; speedup vs baseline: 1.5786x; 1.0715x over previous
//
#include <hip/hip_runtime.h>
#include <math.h>

typedef float f32x4 __attribute__((ext_vector_type(4)));
typedef short bf16x8 __attribute__((ext_vector_type(8)));
typedef unsigned u32x4 __attribute__((ext_vector_type(4)));

#define DEV static __device__ __forceinline__

constexpr int MROWS = 16384;            // B*T = 256*64
constexpr long long MD = 4194304LL;     // MROWS*256
constexpr long long DTZ = 4718592LL;    // MROWS*288
constexpr float L2E = 1.44269504088896f;
constexpr float LN2 = 0.69314718055995f;

DEV short f2bf(float f) {
  unsigned u = __float_as_uint(f);
  u += 0x7fffu + ((u >> 16) & 1u);
  return (short)(u >> 16);
}
DEV float wredsum(float v) {
#pragma unroll
  for (int off = 32; off > 0; off >>= 1) v += __shfl_xor(v, off, 64);
  return v;
}
DEV float gelu_f(float x) { return 0.5f * x * (1.f + erff(x * 0.70710678118654752f)); }
DEV float softplus_fast(float x) {
  return (x > 20.f) ? x : log2f(1.f + exp2f(x * L2E)) * LN2;
}
DEV float sigmoid_fast(float x) { return 1.f / (1.f + exp2f(-x * L2E)); }

// ---------------------------------------------------------------- GEMM ------
enum { E_NONE = 0, E_BIAS = 1, E_BIAS_RES = 2, E_GELU_BIAS = 3, E_SIM = 4, E_CONV = 5 };

// C[M,N] = epi(A[M,K] @ W[N,K]^T). Tile 128x64, 256 threads (4 waves 2x2,
// wave tile 64x32). Register-prefetch pipeline; LDS 27.6KB -> 5 blocks/CU.
template <int EPI>
__global__ __launch_bounds__(256) void gemm128(
    const float* __restrict__ A, const float* __restrict__ W, float* __restrict__ C,
    const float* __restrict__ bias, const float* __restrict__ res,
    int K, int ldc,
    long long az, long long wz, long long cz, long long bz,
    const float* __restrict__ xa, const float* __restrict__ xt) {
  constexpr int SBYTES = (EPI == E_CONV) ? 33280 : 27648;
  __shared__ __align__(16) char smem[SBYTES];
  short* As = (short*)smem;            // [128][72]
  short* Bs = As + 128 * 72;           // [64][72]
  const int z = blockIdx.z;
  A += (long long)z * az;
  W += (long long)z * wz;
  C += (long long)z * cz;
  const float* bi = bias ? bias + (long long)z * bz : bias;
  const int tid = threadIdx.x, lane = tid & 63, wid = tid >> 6;
  const int wm = wid >> 1, wn = wid & 1;
  const int rowBase = blockIdx.y * 128, colBase = blockIdx.x * 64;
  f32x4 acc[4][2];
#pragma unroll
  for (int m = 0; m < 4; ++m)
#pragma unroll
    for (int n = 0; n < 2; ++n) acc[m][n] = f32x4{0.f, 0.f, 0.f, 0.f};
  const int sr = tid >> 3, sc = (tid & 7) << 3;
  f32x4 ra[4][2], rb[2][2];

#define GLOAD(K0)                                                              \
  {                                                                            \
    _Pragma("unroll") for (int p = 0; p < 4; ++p) {                            \
      const float* sa = A + (long long)(rowBase + p * 32 + sr) * K + ((K0) + sc); \
      ra[p][0] = *(const f32x4*)sa;                                            \
      ra[p][1] = *(const f32x4*)(sa + 4);                                      \
    }                                                                          \
    _Pragma("unroll") for (int q = 0; q < 2; ++q) {                            \
      int wr = colBase + q * 32 + sr;                                          \
      wr = (wr < ldc) ? wr : (ldc - 1);                                        \
      const float* sb = W + (long long)wr * K + ((K0) + sc);                   \
      rb[q][0] = *(const f32x4*)sb;                                            \
      rb[q][1] = *(const f32x4*)(sb + 4);                                      \
    }                                                                          \
  }

  GLOAD(0);
  const int nsteps = K >> 6;
  for (int s = 0; s < nsteps; ++s) {
    __syncthreads();
#pragma unroll
    for (int p = 0; p < 4; ++p) {
      bf16x8 pa;
      pa[0] = f2bf(ra[p][0][0]); pa[1] = f2bf(ra[p][0][1]);
      pa[2] = f2bf(ra[p][0][2]); pa[3] = f2bf(ra[p][0][3]);
      pa[4] = f2bf(ra[p][1][0]); pa[5] = f2bf(ra[p][1][1]);
      pa[6] = f2bf(ra[p][1][2]); pa[7] = f2bf(ra[p][1][3]);
      *(bf16x8*)&As[(p * 32 + sr) * 72 + sc] = pa;
    }
#pragma unroll
    for (int q = 0; q < 2; ++q) {
      bf16x8 pb;
      pb[0] = f2bf(rb[q][0][0]); pb[1] = f2bf(rb[q][0][1]);
      pb[2] = f2bf(rb[q][0][2]); pb[3] = f2bf(rb[q][0][3]);
      pb[4] = f2bf(rb[q][1][0]); pb[5] = f2bf(rb[q][1][1]);
      pb[6] = f2bf(rb[q][1][2]); pb[7] = f2bf(rb[q][1][3]);
      *(bf16x8*)&Bs[(q * 32 + sr) * 72 + sc] = pb;
    }
    if (s + 1 < nsteps) GLOAD((s + 1) << 6);
    __syncthreads();
#pragma unroll
    for (int ks = 0; ks < 2; ++ks) {
      const int kb = ks * 32 + (lane >> 4) * 8;
      bf16x8 af[4], bw[2];
#pragma unroll
      for (int m = 0; m < 4; ++m)
        af[m] = *(const bf16x8*)&As[(wm * 64 + m * 16 + (lane & 15)) * 72 + kb];
#pragma unroll
      for (int n = 0; n < 2; ++n)
        bw[n] = *(const bf16x8*)&Bs[(wn * 32 + n * 16 + (lane & 15)) * 72 + kb];
#pragma unroll
      for (int m = 0; m < 4; ++m)
#pragma unroll
        for (int n = 0; n < 2; ++n)
          acc[m][n] = __builtin_amdgcn_mfma_f32_16x16x32_bf16(af[m], bw[n], acc[m][n], 0, 0, 0);
    }
  }
#undef GLOAD

  if constexpr (EPI == E_CONV) {
    float* SX = (float*)smem;
    __syncthreads();
#pragma unroll
    for (int m = 0; m < 4; ++m)
#pragma unroll
      for (int n = 0; n < 2; ++n)
#pragma unroll
        for (int r = 0; r < 4; ++r) {
          const int rl = wm * 64 + m * 16 + ((lane >> 4) << 2) + r;
          const int cl = wn * 32 + n * 16 + (lane & 15);
          SX[rl * 65 + cl] = acc[m][n][r];
        }
    __syncthreads();
    const int c = tid & 63, rg = tid >> 6;
    const int gcol = colBase + c;
    const float* cwp = xa + (long long)z * 1024 + gcol * 4;
    const float wv0 = cwp[0], wv1 = cwp[1], wv2 = cwp[2], wv3 = cwp[3];
    const float cbv = xt[z * 256 + gcol];
#pragma unroll 4
    for (int i = 0; i < 32; ++i) {
      const int lr = rg * 32 + i;
      const int seq = lr >> 6, tau = lr & 63;
      float a = cbv;
#pragma unroll
      for (int k = 0; k < 4; ++k) {
        const int sidx = tau - 3 + k;
        if (sidx >= 0) {
          const int srow = seq * 64 + (z ? 63 - sidx : sidx);
          const float wk = (k == 0) ? wv0 : (k == 1) ? wv1 : (k == 2) ? wv2 : wv3;
          a += SX[srow * 65 + c] * wk;
        }
      }
      a = a * sigmoid_fast(a);
      C[(long long)(rowBase + lr) * ldc + gcol] = a;
    }
    return;
  }

  float sps = 0.f;
  if (EPI == E_SIM) sps = softplus_fast(xt[0]);
#pragma unroll
  for (int m = 0; m < 4; ++m)
#pragma unroll
    for (int n = 0; n < 2; ++n)
#pragma unroll
      for (int r = 0; r < 4; ++r) {
        const int row = rowBase + wm * 64 + m * 16 + ((lane >> 4) << 2) + r;
        const int col = colBase + wn * 32 + n * 16 + (lane & 15);
        if (col < ldc) {
          float v = acc[m][n][r];
          if (EPI == E_BIAS || EPI == E_BIAS_RES || EPI == E_GELU_BIAS) v += bi[col];
          if (EPI == E_BIAS_RES) v += res[(long long)row * ldc + col];
          if (EPI == E_GELU_BIAS) v = gelu_f(v);
          if (EPI == E_SIM) {
            v = v * sps + bi[col];
            const float al = 1.f / (1.f + expf(-xa[col]));
            v = al * v + (1.f - al) * res[(long long)row * ldc + col];
          }
          C[(long long)row * ldc + col] = v;
        }
      }
}

// --------------------------------------------------------------- helpers ----
__global__ __launch_bounds__(256) void prep_wcat(
    const float* __restrict__ dt_w, const float* __restrict__ dt_b,
    const float* __restrict__ Bw, const float* __restrict__ Cw,
    float* __restrict__ wcat, float* __restrict__ bcat) {
  const int r = blockIdx.x, ld = blockIdx.y, tid = threadIdx.x;
  float v;
  if (r < 256)      v = dt_w[(long long)ld * 65536 + r * 256 + tid];
  else if (r < 272) v = Bw[(long long)ld * 4096 + (r - 256) * 256 + tid];
  else              v = Cw[(long long)ld * 4096 + (r - 272) * 256 + tid];
  wcat[(long long)ld * 98304 + (long long)r * 256 + tid] = v;
  if (r == 0) bcat[ld * 288 + tid] = dt_b[ld * 256 + tid];
  if (r == 1 && tid < 32) bcat[ld * 288 + 256 + tid] = 0.f;
}

__global__ __launch_bounds__(256) void meta_kernel(
    const int* __restrict__ site_ids, const int* __restrict__ hours,
    const float* __restrict__ site_emb, const float* __restrict__ hour_emb,
    const float* __restrict__ meta_w, const float* __restrict__ meta_b,
    float* __restrict__ out) {
  const int b = blockIdx.x, d = threadIdx.x;
  const int si = site_ids[b], hr = hours[b];
  const float* mw = meta_w + d * 32;
  float acc = meta_b[d];
#pragma unroll
  for (int m = 0; m < 16; ++m) acc += site_emb[si * 16 + m] * mw[m];
#pragma unroll
  for (int m = 0; m < 16; ++m) acc += hour_emb[hr * 16 + m] * mw[16 + m];
  out[b * 256 + d] = acc;
}

// LN, 4 rows/block (1 wave/row), f32x4 loads, no barriers.
template <int MODE>
__global__ __launch_bounds__(256) void ln_kernel(
    const float* __restrict__ in, float* __restrict__ out,
    const float* __restrict__ g, const float* __restrict__ bta,
    const float* __restrict__ pos, const float* __restrict__ mta) {
  const int row = blockIdx.x * 4 + (threadIdx.x >> 6);
  const int lane = threadIdx.x & 63;
  const long long base = (long long)row * 256 + lane * 4;
  f32x4 v = *(const f32x4*)(in + base);
  const float mean = wredsum(v[0] + v[1] + v[2] + v[3]) * (1.f / 256.f);
  f32x4 c = {v[0] - mean, v[1] - mean, v[2] - mean, v[3] - mean};
  const float var = wredsum(c[0] * c[0] + c[1] * c[1] + c[2] * c[2] + c[3] * c[3]) * (1.f / 256.f);
  const float rs = rsqrtf(var + 1e-5f);
  const f32x4 gv = *(const f32x4*)(g + lane * 4);
  const f32x4 bv = *(const f32x4*)(bta + lane * 4);
  f32x4 y;
#pragma unroll
  for (int j = 0; j < 4; ++j) y[j] = c[j] * rs * gv[j] + bv[j];
  if (MODE == 1) {
    const f32x4 pv = *(const f32x4*)(pos + (row & 63) * 256 + lane * 4);
    const f32x4 mv = *(const f32x4*)(mta + (row >> 6) * 256 + lane * 4);
#pragma unroll
    for (int j = 0; j < 4; ++j) y[j] = gelu_f(y[j]) + pv[j] + mv[j];
  }
  *(f32x4*)(out + base) = y;
}

// selective scan: thread = (b,d); dt/B/C from fused dtbc [16384,288] per dir.
__global__ __launch_bounds__(256) void scan_kernel(
    const float* __restrict__ dtbc, const float* __restrict__ x,
    float* __restrict__ hcat, const float* __restrict__ alog,
    const float* __restrict__ Dpl) {
  __shared__ float bcs[2048];
  const int b = blockIdx.x, dir = blockIdx.y, d = threadIdx.x;
  const float* dz = dtbc + (long long)dir * DTZ;
  for (int idx = d; idx < 2048; idx += 256)
    bcs[idx] = dz[(long long)(b * 64 + (idx >> 5)) * 288 + 256 + (idx & 31)];
  float an2[16];
  const float* al = alog + ((long long)dir * 256 + d) * 16;
#pragma unroll
  for (int n = 0; n < 16; ++n) an2[n] = -expf(al[n]) * L2E;
  const float dp = Dpl[dir * 256 + d];
  float hs[16];
#pragma unroll
  for (int n = 0; n < 16; ++n) hs[n] = 0.f;
  __syncthreads();
  const float* dtr = dz + (long long)b * 64 * 288 + d;
  const float* xr = x + (long long)b * 64 * 256 + d;
  float draw = dtr[0];
  float xv = xr[(dir ? 63 : 0) * 256];
  for (int tau = 0; tau < 64; ++tau) {
    float drawN = 0.f, xvN = 0.f;
    if (tau < 63) {
      drawN = dtr[(tau + 1) * 288];
      xvN = xr[(dir ? (62 - tau) : (tau + 1)) * 256];
    }
    const float dtv = softplus_fast(draw);
    const float u = xv * dtv;
    float y = 0.f;
#pragma unroll
    for (int n = 0; n < 16; ++n) {
      const float dA = exp2f(an2[n] * dtv);
      hs[n] = hs[n] * dA + u * bcs[tau * 32 + n];
      y += hs[n] * bcs[tau * 32 + 16 + n];
    }
    const int to = dir ? 63 - tau : tau;
    hcat[(long long)(b * 64 + to) * 512 + dir * 256 + d] = y + xv * dp;
    draw = drawN; xv = xvN;
  }
}

// MFMA attention: 1 wave per (b,head). S^T = mfma(K,Q) -> softmax in-lane ->
// P packed bf16 -> PV B-frags via shfl -> O^T = mfma(V^T, P^T).
// C-layout (verified): col = lane&15, row = (lane>>4)*4 + reg.
__global__ __launch_bounds__(64) void attn_kernel(
    const float* __restrict__ qkv, float* __restrict__ out) {
  __shared__ __align__(16) char smem[3 * 64 * 72 * 2];   // 27648 B
  short* qs  = (short*)smem;           // [64][72] bf16, rows i
  short* kss = qs + 64 * 72;           // [64][72] bf16, rows j
  short* vts = kss + 64 * 72;          // [64][72] bf16, rows e (V^T)
  const int b = blockIdx.x, h = blockIdx.y, lane = threadIdx.x;
  const long long rb = (long long)b * 64;
  const float* base = qkv + rb * 768 + h * 64;
  const int t3 = lane >> 3, oct = lane & 7;
  // stage Q,K (8 rows x 8 octets per pass)
#pragma unroll
  for (int p = 0; p < 8; ++p) {
    const int r = p * 8 + t3;
    const float* qp = base + (long long)r * 768 + oct * 8;
    f32x4 a0 = *(const f32x4*)qp, a1 = *(const f32x4*)(qp + 4);
    bf16x8 pa;
    pa[0] = f2bf(a0[0]); pa[1] = f2bf(a0[1]); pa[2] = f2bf(a0[2]); pa[3] = f2bf(a0[3]);
    pa[4] = f2bf(a1[0]); pa[5] = f2bf(a1[1]); pa[6] = f2bf(a1[2]); pa[7] = f2bf(a1[3]);
    *(bf16x8*)&qs[r * 72 + oct * 8] = pa;
    const float* kp = qp + 256;
    f32x4 b0 = *(const f32x4*)kp, b1 = *(const f32x4*)(kp + 4);
    bf16x8 pb;
    pb[0] = f2bf(b0[0]); pb[1] = f2bf(b0[1]); pb[2] = f2bf(b0[2]); pb[3] = f2bf(b0[3]);
    pb[4] = f2bf(b1[0]); pb[5] = f2bf(b1[1]); pb[6] = f2bf(b1[2]); pb[7] = f2bf(b1[3]);
    *(bf16x8*)&kss[r * 72 + oct * 8] = pb;
  }
  // stage V transposed: lane owns V row `lane`, scatters down column `lane`
  {
    f32x4 vr[16];
#pragma unroll
    for (int c = 0; c < 16; ++c)
      vr[c] = *(const f32x4*)(base + (long long)lane * 768 + 512 + c * 4);
#pragma unroll
    for (int ee = 0; ee < 64; ++ee)
      vts[ee * 72 + lane] = f2bf(vr[ee >> 2][ee & 3]);
  }
  __syncthreads();
  const int g = lane >> 4, i16 = lane & 15;
  // S^T[j][i] = sum_e K[j][e] Q[i][e], tiles [jt][it]
  f32x4 acc_s[4][4];
#pragma unroll
  for (int jt = 0; jt < 4; ++jt)
#pragma unroll
    for (int it = 0; it < 4; ++it) acc_s[jt][it] = f32x4{0.f, 0.f, 0.f, 0.f};
#pragma unroll
  for (int ks2 = 0; ks2 < 2; ++ks2) {
    const int e0 = ks2 * 32 + g * 8;
    bf16x8 af[4], bq[4];
#pragma unroll
    for (int jt = 0; jt < 4; ++jt)
      af[jt] = *(const bf16x8*)&kss[(jt * 16 + i16) * 72 + e0];
#pragma unroll
    for (int it = 0; it < 4; ++it)
      bq[it] = *(const bf16x8*)&qs[(it * 16 + i16) * 72 + e0];
#pragma unroll
    for (int jt = 0; jt < 4; ++jt)
#pragma unroll
      for (int it = 0; it < 4; ++it)
        acc_s[jt][it] = __builtin_amdgcn_mfma_f32_16x16x32_bf16(af[jt], bq[it], acc_s[jt][it], 0, 0, 0);
  }
  // softmax per query i (= it*16 + i16); reduce across g via shfl_xor 16,32
  float inv[4];
  unsigned pu[4][4][2];   // packed bf16 P, [jt][it][word] word = regs (0,1),(2,3)
#pragma unroll
  for (int it = 0; it < 4; ++it) {
    float m = -1e30f;
#pragma unroll
    for (int jt = 0; jt < 4; ++jt)
#pragma unroll
      for (int r = 0; r < 4; ++r) {
        acc_s[jt][it][r] *= 0.125f;
        m = fmaxf(m, acc_s[jt][it][r]);
      }
    m = fmaxf(m, __shfl_xor(m, 16, 64));
    m = fmaxf(m, __shfl_xor(m, 32, 64));
    float sum = 0.f;
#pragma unroll
    for (int jt = 0; jt < 4; ++jt)
#pragma unroll
      for (int r = 0; r < 4; ++r) {
        const float pv = exp2f((acc_s[jt][it][r] - m) * L2E);
        acc_s[jt][it][r] = pv;
        sum += pv;
      }
    sum += __shfl_xor(sum, 16, 64);
    sum += __shfl_xor(sum, 32, 64);
    inv[it] = 1.f / sum;
#pragma unroll
    for (int jt = 0; jt < 4; ++jt) {
      pu[jt][it][0] = ((unsigned)(unsigned short)f2bf(acc_s[jt][it][1]) << 16) |
                      (unsigned)(unsigned short)f2bf(acc_s[jt][it][0]);
      pu[jt][it][1] = ((unsigned)(unsigned short)f2bf(acc_s[jt][it][3]) << 16) |
                      (unsigned)(unsigned short)f2bf(acc_s[jt][it][2]);
    }
  }
  // O^T[e][i] = sum_j V^T[e][j] P^T[j][i], tiles [mt][it]
  f32x4 acc_o[4][4];
#pragma unroll
  for (int mt = 0; mt < 4; ++mt)
#pragma unroll
    for (int it = 0; it < 4; ++it) acc_o[mt][it] = f32x4{0.f, 0.f, 0.f, 0.f};
  const int srcA = ((lane >> 4) & 1) * 32 + i16;   // (2*(g&1))*16 + i16
  const int srcB = srcA + 16;
  const bool hi = (lane & 32) != 0;                // g>>1
#pragma unroll
  for (int ks2 = 0; ks2 < 2; ++ks2) {
    const int j0 = ks2 * 32 + g * 8;
    bf16x8 av[4];
#pragma unroll
    for (int mt = 0; mt < 4; ++mt)
      av[mt] = *(const bf16x8*)&vts[(mt * 16 + i16) * 72 + j0];
#pragma unroll
    for (int it = 0; it < 4; ++it) {
      unsigned w[4];
#pragma unroll
      for (int wd = 0; wd < 2; ++wd) {
        const unsigned loA = (unsigned)__shfl((int)pu[2 * ks2 + 0][it][wd], srcA, 64);
        const unsigned hiA = (unsigned)__shfl((int)pu[2 * ks2 + 1][it][wd], srcA, 64);
        w[wd] = hi ? hiA : loA;
        const unsigned loB = (unsigned)__shfl((int)pu[2 * ks2 + 0][it][wd], srcB, 64);
        const unsigned hiB = (unsigned)__shfl((int)pu[2 * ks2 + 1][it][wd], srcB, 64);
        w[2 + wd] = hi ? hiB : loB;
      }
      const u32x4 bb = {w[0], w[1], w[2], w[3]};
      const bf16x8 pb = __builtin_bit_cast(bf16x8, bb);
#pragma unroll
      for (int mt = 0; mt < 4; ++mt)
        acc_o[mt][it] = __builtin_amdgcn_mfma_f32_16x16x32_bf16(av[mt], pb, acc_o[mt][it], 0, 0, 0);
    }
  }
  // writeback via LDS (coalesced): ot[i][e] f32 stride 68, aliases qs/kss
  __syncthreads();
  float* ot = (float*)smem;
#pragma unroll
  for (int mt = 0; mt < 4; ++mt)
#pragma unroll
    for (int it = 0; it < 4; ++it)
#pragma unroll
      for (int r = 0; r < 4; ++r)
        ot[(it * 16 + i16) * 68 + mt * 16 + g * 4 + r] = acc_o[mt][it][r] * inv[it];
  __syncthreads();
  float* orow = out + (rb + lane) * 256 + h * 64;
#pragma unroll
  for (int c = 0; c < 16; ++c)
    *(f32x4*)(orow + c * 4) = *(const f32x4*)&ot[lane * 68 + c * 4];
}

// row-l2norm of h -> hn; also copy h to out1. 4 rows/block, f32x4.
__global__ __launch_bounds__(256) void hn_kernel(
    const float* __restrict__ in, float* __restrict__ hn, float* __restrict__ out1) {
  const int row = blockIdx.x * 4 + (threadIdx.x >> 6);
  const int lane = threadIdx.x & 63;
  const long long base = (long long)row * 256 + lane * 4;
  f32x4 v = *(const f32x4*)(in + base);
  const float ss = wredsum(v[0] * v[0] + v[1] * v[1] + v[2] * v[2] + v[3] * v[3]);
  const float inv = 1.f / fmaxf(sqrtf(ss), 1e-12f);
  f32x4 y = {v[0] * inv, v[1] * inv, v[2] * inv, v[3] * inv};
  *(f32x4*)(hn + base) = y;
  *(f32x4*)(out1 + base) = v;
}

// l2norm prototypes into padded [256,256] buffer (rows >=234 zeroed)
__global__ __launch_bounds__(256) void protonorm_kernel(
    const float* __restrict__ proto, float* __restrict__ pn) {
  __shared__ float red[4];
  const int c = blockIdx.x, d = threadIdx.x;
  const float v = (c < 234) ? proto[(long long)c * 256 + d] : 0.f;
  float s = wredsum(v * v);
  if ((d & 63) == 0) red[d >> 6] = s;
  __syncthreads();
  const float ss = red[0] + red[1] + red[2] + red[3];
  const float inv = (c < 234) ? 1.f / fmaxf(sqrtf(ss), 1e-12f) : 0.f;
  pn[(long long)c * 256 + d] = v * inv;
}

// ------------------------------------------------------------------ host ----
extern "C" void kernel_launch(void* const* d_in, const int* in_sizes, int n_in,
                              void* d_out, int out_size, void* d_ws, size_t ws_size,
                              hipStream_t stream) {
  const float* emb       = (const float*)d_in[0];
  const float* perch     = (const float*)d_in[1];
  const int*   site_ids  = (const int*)d_in[2];
  const int*   hours     = (const int*)d_in[3];
  const float* in_w      = (const float*)d_in[4];
  const float* in_b      = (const float*)d_in[5];
  const float* ln0_g     = (const float*)d_in[6];
  const float* ln0_b     = (const float*)d_in[7];
  const float* pos_enc   = (const float*)d_in[8];
  const float* site_emb  = (const float*)d_in[9];
  const float* hour_emb  = (const float*)d_in[10];
  const float* meta_w    = (const float*)d_in[11];
  const float* meta_b    = (const float*)d_in[12];
  const float* ssm_in_w  = (const float*)d_in[13];
  const float* ssm_cw    = (const float*)d_in[14];
  const float* ssm_cb    = (const float*)d_in[15];
  const float* ssm_dt_w  = (const float*)d_in[16];
  const float* ssm_dt_b  = (const float*)d_in[17];
  const float* ssm_Alog  = (const float*)d_in[18];
  const float* ssm_Dp    = (const float*)d_in[19];
  const float* ssm_B_w   = (const float*)d_in[20];
  const float* ssm_C_w   = (const float*)d_in[21];
  const float* merge_w   = (const float*)d_in[22];
  const float* merge_b   = (const float*)d_in[23];
  const float* ln_g      = (const float*)d_in[24];
  const float* ln_b      = (const float*)d_in[25];
  const float* qkv_w     = (const float*)d_in[26];
  const float* qkv_b     = (const float*)d_in[27];
  const float* ao_w      = (const float*)d_in[28];
  const float* ao_b      = (const float*)d_in[29];
  const float* ca1_g     = (const float*)d_in[30];
  const float* ca1_b     = (const float*)d_in[31];
  const float* ffn_w1    = (const float*)d_in[32];
  const float* ffn_b1    = (const float*)d_in[33];
  const float* ffn_w2    = (const float*)d_in[34];
  const float* ffn_b2    = (const float*)d_in[35];
  const float* ca2_g     = (const float*)d_in[36];
  const float* ca2_b     = (const float*)d_in[37];
  const float* protos    = (const float*)d_in[38];
  const float* ptemp     = (const float*)d_in[39];
  const float* cbias     = (const float*)d_in[40];
  const float* falpha    = (const float*)d_in[41];

  float* out0 = (float*)d_out;                    // species_logits [16384,234]
  float* out1 = out0 + (long long)MROWS * 234;    // h              [16384,256]

  float* ws = (float*)d_ws;
  float* w_meta = ws;                         // 65536
  float* w_h    = ws + 65536;                 // MD
  float* w_tpre = w_h + MD;                   // MD
  float* w_ar   = w_tpre + MD;                // arena
  float* w_xc   = w_ar;                       // 2*MD
  float* w_dtbc = w_ar + 2 * MD;              // 2*DTZ
  float* w_wcat = w_ar + 2 * MD + 2 * DTZ;    // 4*98304
  float* w_bcat = w_wcat + 393216;            // 4*288
  float* w_z    = w_ar;                       // MD
  float* w_qkv  = w_ar + MD;                  // 12582912
  float* w_mid  = w_ar + MD;                  // 8388608
  float* w_hn   = w_ar;                       // MD
  float* w_pn   = w_ar + MD;                  // 65536

  const dim3 blk(256);

  prep_wcat<<<dim3(288, 4), blk, 0, stream>>>(ssm_dt_w, ssm_dt_b, ssm_B_w,
                                              ssm_C_w, w_wcat, w_bcat);
  meta_kernel<<<256, blk, 0, stream>>>(site_ids, hours, site_emb, hour_emb,
                                       meta_w, meta_b, w_meta);
  gemm128<E_BIAS><<<dim3(4, 128, 1), blk, 0, stream>>>(
      emb, in_w, w_tpre, in_b, nullptr, 1536, 256, 0, 0, 0, 0, nullptr, nullptr);
  ln_kernel<1><<<MROWS / 4, blk, 0, stream>>>(w_tpre, w_h, ln0_g, ln0_b, pos_enc, w_meta);

  for (int l = 0; l < 2; ++l) {
    const float* inw_l = ssm_in_w + (long long)l * 262144;
    const float* cw_l  = ssm_cw + l * 2048;
    const float* cb_l  = ssm_cb + l * 512;
    const float* Al_l  = ssm_Alog + l * 8192;
    const float* Dp_l  = ssm_Dp + l * 512;

    gemm128<E_CONV><<<dim3(4, 128, 2), blk, 0, stream>>>(
        w_h, inw_l, w_xc, nullptr, nullptr, 256, 256,
        0LL, 131072LL, MD, 0LL, cw_l, cb_l);
    gemm128<E_BIAS><<<dim3(5, 128, 2), blk, 0, stream>>>(
        w_xc, w_wcat + (long long)l * 196608, w_dtbc,
        w_bcat + l * 576, nullptr, 256, 288,
        MD, 98304LL, DTZ, 288LL, nullptr, nullptr);
    scan_kernel<<<dim3(256, 2), blk, 0, stream>>>(w_dtbc, w_h, w_xc, Al_l, Dp_l);
    gemm128<E_BIAS_RES><<<dim3(4, 128, 1), blk, 0, stream>>>(
        w_xc, merge_w + (long long)l * 131072, w_tpre, merge_b + l * 256, w_h,
        512, 256, 0, 0, 0, 0, nullptr, nullptr);
    ln_kernel<0><<<MROWS / 4, blk, 0, stream>>>(w_tpre, w_h, ln_g + l * 256, ln_b + l * 256,
                                                nullptr, nullptr);
  }

  // cross attention
  ln_kernel<0><<<MROWS / 4, blk, 0, stream>>>(w_h, w_z, ca1_g, ca1_b, nullptr, nullptr);
  gemm128<E_BIAS><<<dim3(12, 128, 1), blk, 0, stream>>>(
      w_z, qkv_w, w_qkv, qkv_b, nullptr, 256, 768, 0, 0, 0, 0, nullptr, nullptr);
  attn_kernel<<<dim3(256, 4), dim3(64), 0, stream>>>(w_qkv, w_tpre);
  gemm128<E_BIAS_RES><<<dim3(4, 128, 1), blk, 0, stream>>>(
      w_tpre, ao_w, w_h, ao_b, w_h, 256, 256, 0, 0, 0, 0, nullptr, nullptr);

  // FFN
  ln_kernel<0><<<MROWS / 4, blk, 0, stream>>>(w_h, w_z, ca2_g, ca2_b, nullptr, nullptr);
  gemm128<E_GELU_BIAS><<<dim3(8, 128, 1), blk, 0, stream>>>(
      w_z, ffn_w1, w_mid, ffn_b1, nullptr, 256, 512, 0, 0, 0, 0, nullptr, nullptr);
  gemm128<E_BIAS_RES><<<dim3(4, 128, 1), blk, 0, stream>>>(
      w_mid, ffn_w2, w_h, ffn_b2, w_h, 512, 256, 0, 0, 0, 0, nullptr, nullptr);

  // prototype head
  protonorm_kernel<<<256, blk, 0, stream>>>(protos, w_pn);
  hn_kernel<<<MROWS / 4, blk, 0, stream>>>(w_h, w_hn, out1);
  gemm128<E_SIM><<<dim3(4, 128, 1), blk, 0, stream>>>(
      w_hn, w_pn, out0, cbias, perch, 256, 234, 0, 0, 0, 0, falpha, ptemp);

  (void)in_sizes; (void)n_in; (void)out_size; (void)ws_size;
}